// Round 8
// baseline (334.879 us; speedup 1.0000x reference)
//
#include <hip/hip_runtime.h>
#include <hip/hip_bf16.h>

#define DEVI __device__ __forceinline__

constexpr int kS  = 2048;
constexpr int kH  = 1024;
constexpr int kD  = 64;
constexpr int kBS = 4096;            // B*S
constexpr int kHeadEls = kS * kD;    // elements per (b,head) chunk

typedef __attribute__((ext_vector_type(4))) float f32x4;
typedef __attribute__((ext_vector_type(8))) __bf16 bf16x8;
typedef __attribute__((ext_vector_type(8))) unsigned short u16x8;
typedef __attribute__((ext_vector_type(2))) unsigned int u32x2;

DEVI unsigned short f2bf(float f) {            // RNE fp32 -> bf16
  unsigned int u = __builtin_bit_cast(unsigned int, f);
  u = u + 0x7FFFu + ((u >> 16) & 1u);
  return (unsigned short)(u >> 16);
}
DEVI float fast_exp2(float x) { float r; asm("v_exp_f32 %0, %1" : "=v"(r) : "v"(x)); return r; }
DEVI unsigned int cvt_pk(float lo, float hi) {
  unsigned int r; asm("v_cvt_pk_bf16_f32 %0, %1, %2" : "=v"(r) : "v"(lo), "v"(hi)); return r;
}
DEVI bf16x8 cvt8(const f32x4 a, const f32x4 b) {
  union { unsigned int u[4]; bf16x8 v; } r;
  r.u[0] = cvt_pk(a[0], a[1]); r.u[1] = cvt_pk(a[2], a[3]);
  r.u[2] = cvt_pk(b[0], b[1]); r.u[3] = cvt_pk(b[2], b[3]);
  return r.v;
}

#define GLDS16(g, l) __builtin_amdgcn_global_load_lds( \
    (const __attribute__((address_space(1))) void*)(g), \
    (__attribute__((address_space(3))) void*)(l), 16, 0, 0)

// ---------------------------------------------------------------------------
// fp32 -> bf16 pre-convert: q,k,v (4M els each) and Wq,Wk,Wv (1M each) into
// the AW-region stash (AW is only written later by attn_main).
// ---------------------------------------------------------------------------
__global__ __launch_bounds__(256) void cvt_all(
    const float* __restrict__ q, const float* __restrict__ k, const float* __restrict__ v,
    const float* __restrict__ Wq, const float* __restrict__ Wk, const float* __restrict__ Wv,
    unsigned short* __restrict__ stash)
{
  const int z = blockIdx.y, x = blockIdx.x;
  const float* s;
  unsigned short* d;
  size_t i;
  if (x < 2048) {
    s = z == 0 ? q : z == 1 ? k : v;
    d = stash + (size_t)z * 4194304;
    i = ((size_t)x * 256 + threadIdx.x) * 8;
  } else {
    s = z == 0 ? Wq : z == 1 ? Wk : Wv;
    d = stash + (size_t)12582912 + (size_t)z * 1048576;
    i = ((size_t)(x - 2048) * 256 + threadIdx.x) * 8;
  }
  f32x4 a = *(const f32x4*)(s + i);
  f32x4 b = *(const f32x4*)(s + i + 4);
  union { unsigned int u[4]; u16x8 v; } r;
  r.u[0] = cvt_pk(a[0], a[1]); r.u[1] = cvt_pk(a[2], a[3]);
  r.u[2] = cvt_pk(b[0], b[1]); r.u[3] = cvt_pk(b[2], b[3]);
  *(u16x8*)(d + i) = r.v;
}

// ---------------------------------------------------------------------------
// GEMM: C[m,n] = sum_k A[m,k]*B[n,k]  (C = A @ B^T), M=4096 N=1024 K=1024.
// 2-phase double-buffered global_load_lds staging. A always bf16.
// PROJ: B bf16, C bf16 (z==2 -> transposed VPT layout).
// !PROJ: B fp32 (Wo, cvt inline), C fp32 nontemporal.
// ---------------------------------------------------------------------------
template<bool PROJ>
__global__ __launch_bounds__(256, 3) void gemm_k(
    const unsigned short* __restrict__ Aq, const unsigned short* __restrict__ Ak,
    const unsigned short* __restrict__ Av,
    const void* __restrict__ Bq, const void* __restrict__ Bk, const void* __restrict__ Bv,
    void* __restrict__ Cq, void* __restrict__ Ck, void* __restrict__ Cv)
{
  constexpr int K = kH;
  __shared__ __align__(16) unsigned char As[2][8192];
  __shared__ __align__(16) unsigned char Bs[2][PROJ ? 8192 : 16384];

  const int z = PROJ ? blockIdx.z : 0;
  const unsigned short* Ap = z == 0 ? Aq : z == 1 ? Ak : Av;
  const void* Bp = z == 0 ? Bq : z == 1 ? Bk : Bv;
  void*       Cp = z == 0 ? Cq : z == 1 ? Ck : Cv;

  const int tid  = threadIdx.x;
  const int lane = tid & 63, wv = tid >> 6;
  const int l15  = lane & 15, lg = lane >> 4;
  const int m0 = blockIdx.y * 128, n0 = blockIdx.x * 128;
  const int wM = (wv & 1) * 64, wN = (wv >> 1) * 64;

  const char* aSrc[2];
#pragma unroll
  for (int c = 0; c < 2; ++c) {
    const int row = c * 64 + (tid >> 2);
    const int cb  = ((tid & 3) * 16) ^ (((row >> 1) & 3) << 4);
    aSrc[c] = (const char*)Ap + ((size_t)(m0 + row) * K) * 2 + cb;
  }
  const char* bSrc[PROJ ? 2 : 4];
  if constexpr (PROJ) {
#pragma unroll
    for (int c = 0; c < 2; ++c) {
      const int row = c * 64 + (tid >> 2);
      const int cb  = ((tid & 3) * 16) ^ (((row >> 1) & 3) << 4);
      bSrc[c] = (const char*)Bp + ((size_t)(n0 + row) * K) * 2 + cb;
    }
  } else {
#pragma unroll
    for (int c = 0; c < 4; ++c) {
      const int row = c * 32 + wv * 8 + (lane >> 3);
      const int cb  = ((lane & 7) * 16) ^ ((row & 7) << 4);
      bSrc[c] = (const char*)Bp + ((size_t)(n0 + row) * K) * 4 + cb;
    }
  }

  int aoff[4], boff[4];
#pragma unroll
  for (int t = 0; t < 4; ++t) {
    const int rA = wM + t * 16 + l15;
    aoff[t] = rA * 64 + ((lg * 16) ^ (((rA >> 1) & 3) << 4));
    const int rB = wN + t * 16 + l15;
    boff[t] = PROJ ? (rB * 64  + ((lg * 16) ^ (((rB >> 1) & 3) << 4)))
                   : (rB * 128 + ((lg * 32) ^ ((rB & 7) << 4)));
  }

  f32x4 acc[4][4];
#pragma unroll
  for (int i = 0; i < 4; ++i)
#pragma unroll
    for (int j = 0; j < 4; ++j) acc[i][j] = {0.f, 0.f, 0.f, 0.f};

  auto STG = [&](int kk, int bb) {
#pragma unroll
    for (int c = 0; c < 2; ++c)
      GLDS16(aSrc[c] + (size_t)kk * 2, &As[bb][c * 4096 + wv * 1024]);
    if constexpr (PROJ) {
#pragma unroll
      for (int c = 0; c < 2; ++c)
        GLDS16(bSrc[c] + (size_t)kk * 2, &Bs[bb][c * 4096 + wv * 1024]);
    } else {
#pragma unroll
      for (int c = 0; c < 4; ++c)
        GLDS16(bSrc[c] + (size_t)kk * 4, &Bs[bb][c * 4096 + wv * 1024]);
    }
  };

  STG(0, 0);
  __syncthreads();
  int cur = 0;
  for (int t = 0; t < K / 32; ++t) {
    if (t < K / 32 - 1) STG((t + 1) * 32, cur ^ 1);
    bf16x8 af[4], bfr[4];
#pragma unroll
    for (int x = 0; x < 4; ++x) {
      af[x] = *(const bf16x8*)&As[cur][aoff[x]];
      if constexpr (PROJ) {
        bfr[x] = *(const bf16x8*)&Bs[cur][boff[x]];
      } else {
        f32x4 q0 = *(const f32x4*)&Bs[cur][boff[x]];
        f32x4 q1 = *(const f32x4*)&Bs[cur][boff[x] ^ 16];
        bfr[x] = cvt8(q0, q1);
      }
    }
#pragma unroll
    for (int mt = 0; mt < 4; ++mt)
#pragma unroll
      for (int nt = 0; nt < 4; ++nt)
        acc[mt][nt] = __builtin_amdgcn_mfma_f32_16x16x32_bf16(af[mt], bfr[nt], acc[mt][nt], 0, 0, 0);
    __syncthreads();   // drains next-tile staging (in flight during compute)
    cur ^= 1;
  }

  if constexpr (PROJ) {
    const bool vmode = (z == 2);
#pragma unroll
    for (int mt = 0; mt < 4; ++mt)
#pragma unroll
      for (int nt = 0; nt < 4; ++nt)
#pragma unroll
        for (int r = 0; r < 4; ++r) {
          const int row = m0 + wM + mt * 16 + lg * 4 + r;
          const int col = n0 + wN + nt * 16 + l15;
          const unsigned short hv = f2bf(acc[mt][nt][r]);
          if (!vmode) {
            ((unsigned short*)Cp)[(size_t)row * kH + col] = hv;
          } else {
            const int bn = row >> 7;                       // VPT[bn][d][j]
            const int j  = ((row & 127) << 4) | (col >> 6);
            const int d  = col & 63;
            ((unsigned short*)Cp)[(size_t)bn * kHeadEls + (size_t)d * kS + j] = hv;
          }
        }
  } else {
#pragma unroll
    for (int mt = 0; mt < 4; ++mt)
#pragma unroll
      for (int nt = 0; nt < 4; ++nt)
#pragma unroll
        for (int r = 0; r < 4; ++r) {
          const int row = m0 + wM + mt * 16 + lg * 4 + r;
          const int col = n0 + wN + nt * 16 + l15;
          __builtin_nontemporal_store(acc[mt][nt][r], (float*)Cp + (size_t)row * kH + col);
        }
  }
}

// ---------------------------------------------------------------------------
// attn_rs: row sums only. 1024 blocks x 2 waves (32 q-rows/wave). K-only LDS
// dbuf (16 KB). Swapped QK^T, same summation order as prior rounds ->
// bit-identical rs. Writes rs to the out region (overwritten later).
// ---------------------------------------------------------------------------
__global__ __launch_bounds__(128, 2) void attn_rs(
    const unsigned short* __restrict__ QP,
    const unsigned short* __restrict__ KP,
    float* __restrict__ rsout)          // [32][2048]
{
  __shared__ __align__(16) unsigned short Kb[2][4096];

  const int tid  = threadIdx.x;
  const int lane = tid & 63, wv = tid >> 6;
  const int l15  = lane & 15, lg = lane >> 4;
  const int f = blockIdx.x;
  const int x = f & 7, r8 = f >> 3;
  const int bn = (r8 >> 5) * 8 + x;     // 4 heads per XCD
  const int i0 = (r8 & 31) * 64;

  const char* Khb = (const char*)(KP + (size_t)bn * kHeadEls);
  const unsigned short* Qh = QP + (size_t)bn * kHeadEls;

  // staging: 4 glds x (128 thr x 16B) = 8 KB tile; pre-swizzled source
  const int srw = tid >> 3, scl = (tid & 7) * 16;
  const int kbase = srw * 128 + (scl ^ ((srw & 7) << 4));

  auto STAGE = [&](int j0, int bb) {
#pragma unroll
    for (int p = 0; p < 4; ++p)
      GLDS16(Khb + (size_t)j0 * 128 + kbase + p * 2048, (char*)Kb[bb] + p * 2048 + tid * 16);
  };

  int koff[4][2];
#pragma unroll
  for (int ct = 0; ct < 4; ++ct) {
    const int rK = ct * 16 + l15;
#pragma unroll
    for (int h = 0; h < 2; ++h)
      koff[ct][h] = rK * 128 + ((h * 64 + lg * 16) ^ ((rK & 7) << 4));
  }

  bf16x8 qf[2][2];
#pragma unroll
  for (int m = 0; m < 2; ++m) {
    const int qr = i0 + wv * 32 + m * 16 + l15;
#pragma unroll
    for (int h = 0; h < 2; ++h)
      qf[m][h] = *(const bf16x8*)(Qh + (size_t)qr * kD + h * 32 + lg * 8);
  }
  const float cexp = 0.18033688011112042f;   // log2(e)/8

  float rs[2] = {0.f, 0.f};
  STAGE(0, 0);
  __syncthreads();
  int cur = 0;
  for (int t = 0; t < 32; ++t) {
    if (t < 31) STAGE((t + 1) * 64, cur ^ 1);
#pragma unroll
    for (int ct = 0; ct < 4; ++ct) {
      const bf16x8 kb0 = *(const bf16x8*)((const char*)Kb[cur] + koff[ct][0]);
      const bf16x8 kb1 = *(const bf16x8*)((const char*)Kb[cur] + koff[ct][1]);
#pragma unroll
      for (int m = 0; m < 2; ++m) {
        f32x4 s = {0.f, 0.f, 0.f, 0.f};
        s = __builtin_amdgcn_mfma_f32_16x16x32_bf16(kb0, qf[m][0], s, 0, 0, 0);
        s = __builtin_amdgcn_mfma_f32_16x16x32_bf16(kb1, qf[m][1], s, 0, 0, 0);
        const float w0 = fast_exp2(s[0] * cexp), w1 = fast_exp2(s[1] * cexp);
        const float w2 = fast_exp2(s[2] * cexp), w3 = fast_exp2(s[3] * cexp);
        rs[m] += (w0 + w1) + (w2 + w3);
      }
    }
    __syncthreads();
    cur ^= 1;
  }
#pragma unroll
  for (int m = 0; m < 2; ++m) {
    rs[m] += __shfl_xor(rs[m], 16, 64);
    rs[m] += __shfl_xor(rs[m], 32, 64);
  }
  if (lg == 0) {
#pragma unroll
    for (int m = 0; m < 2; ++m)
      rsout[(size_t)bn * kS + i0 + wv * 32 + m * 16 + l15] = rs[m];
  }
}

// ---------------------------------------------------------------------------
// attn_main: AW writer + PV fused. 1024 blocks x 2 waves (32 q-rows/wave).
// Per tile: glds(t+1) -> QK^T -> w=exp*inv -> AW store (regular, f32x4) ->
// cvt_pk -> Ws -> PV. Counted vmcnt(8) retires only this wave's glds; the 8
// AW stores stay in flight across the raw s_barrier. PV accumulates
// NORMALIZED P -> XB written directly. LDS 40 KB -> 4 blocks/CU.
// ---------------------------------------------------------------------------
__global__ __launch_bounds__(128, 2) void attn_main(
    const unsigned short* __restrict__ QP,
    const unsigned short* __restrict__ KP,
    const unsigned short* __restrict__ VPT,
    const float* __restrict__ rsb,      // [32][2048]
    float* __restrict__ AW,             // [32][2048][2048] fp32
    unsigned short* __restrict__ XB)    // [4096][1024] bf16
{
  __shared__ __align__(16) unsigned short Kb[2][4096];   // [64 j][64 d] swz
  __shared__ __align__(16) unsigned short Vb[2][4096];   // [64 d][64 j] swz
  __shared__ __align__(16) unsigned short Ws[4096];      // [64 q][64 j] swz

  const int tid  = threadIdx.x;
  const int lane = tid & 63, wv = tid >> 6;
  const int l15  = lane & 15, lg = lane >> 4;
  const int f = blockIdx.x;
  const int x = f & 7, r8 = f >> 3;
  const int bn = (r8 >> 5) * 8 + x;     // 4 heads per XCD
  const int i0 = (r8 & 31) * 64;
  const int b = bn >> 4, n = bn & 15;

  const char* Khb = (const char*)(KP + (size_t)bn * kHeadEls);
  const char* Vhb = (const char*)(VPT + (size_t)bn * kHeadEls);
  const unsigned short* Qh = QP + (size_t)bn * kHeadEls;

  const int srw = tid >> 3, scl = (tid & 7) * 16;
  const int sswz = scl ^ ((srw & 7) << 4);
  const int kbase = srw * 128 + sswz;
  const int vbase = srw * 4096 + sswz;

  auto STAGE_KV = [&](int j0, int bb) {
#pragma unroll
    for (int p = 0; p < 4; ++p) {
      GLDS16(Khb + (size_t)j0 * 128 + kbase + p * 2048,
             (char*)Kb[bb] + p * 2048 + tid * 16);
      GLDS16(Vhb + (size_t)j0 * 2 + vbase + (size_t)p * 65536,
             (char*)Vb[bb] + p * 2048 + tid * 16);
    }
  };

  int koff[4][2], voff[2][4], wswr[2][4], wsrd[2][2];
#pragma unroll
  for (int ct = 0; ct < 4; ++ct) {
    const int rK = ct * 16 + l15;
#pragma unroll
    for (int h = 0; h < 2; ++h)
      koff[ct][h] = rK * 128 + ((h * 64 + lg * 16) ^ ((rK & 7) << 4));
  }
#pragma unroll
  for (int jc = 0; jc < 2; ++jc)
#pragma unroll
    for (int dt = 0; dt < 4; ++dt) {
      const int d = dt * 16 + l15;
      voff[jc][dt] = d * 128 + ((jc * 64 + lg * 16) ^ ((d & 7) << 4));
    }
#pragma unroll
  for (int m = 0; m < 2; ++m) {
    const int rw = wv * 32 + m * 16 + l15;
#pragma unroll
    for (int ct = 0; ct < 4; ++ct)
      wswr[m][ct] = rw * 128 + ((ct * 32 + lg * 8) ^ ((rw & 7) << 4));
#pragma unroll
    for (int jc = 0; jc < 2; ++jc)
      wsrd[m][jc] = rw * 128 + ((jc * 64 + lg * 16) ^ ((rw & 7) << 4));
  }

  bf16x8 qf[2][2];
  float inv[2];
  float* awr[2];
#pragma unroll
  for (int m = 0; m < 2; ++m) {
    const int qr = i0 + wv * 32 + m * 16 + l15;
#pragma unroll
    for (int h = 0; h < 2; ++h)
      qf[m][h] = *(const bf16x8*)(Qh + (size_t)qr * kD + h * 32 + lg * 8);
    inv[m] = 1.0f / rsb[(size_t)bn * kS + qr];
    awr[m] = AW + ((size_t)bn * kS + qr) * kS + lg * 4;
  }
  const float cexp = 0.18033688011112042f;   // log2(e)/8

  f32x4 pv[2][4];
#pragma unroll
  for (int m = 0; m < 2; ++m)
#pragma unroll
    for (int dt = 0; dt < 4; ++dt) pv[m][dt] = {0.f, 0.f, 0.f, 0.f};

  STAGE_KV(0, 0);
  asm volatile("s_waitcnt vmcnt(0) lgkmcnt(0)" ::: "memory");
  __builtin_amdgcn_sched_barrier(0);
  __builtin_amdgcn_s_barrier();

  int cur = 0;
  for (int t = 0; t < 32; ++t) {
    if (t < 31) STAGE_KV((t + 1) * 64, cur ^ 1);   // 8 glds, oldest in queue
    // QK^T (swapped) -> normalized w -> AW store + Ws write
#pragma unroll
    for (int ct = 0; ct < 4; ++ct) {
      const bf16x8 kb0 = *(const bf16x8*)((const char*)Kb[cur] + koff[ct][0]);
      const bf16x8 kb1 = *(const bf16x8*)((const char*)Kb[cur] + koff[ct][1]);
#pragma unroll
      for (int m = 0; m < 2; ++m) {
        f32x4 s = {0.f, 0.f, 0.f, 0.f};
        s = __builtin_amdgcn_mfma_f32_16x16x32_bf16(kb0, qf[m][0], s, 0, 0, 0);
        s = __builtin_amdgcn_mfma_f32_16x16x32_bf16(kb1, qf[m][1], s, 0, 0, 0);
        f32x4 w;
#pragma unroll
        for (int r = 0; r < 4; ++r) w[r] = fast_exp2(s[r] * cexp) * inv[m];
        *(f32x4*)(awr[m] + t * 64 + ct * 16) = w;          // regular store
        u32x2 pk; pk[0] = cvt_pk(w[0], w[1]); pk[1] = cvt_pk(w[2], w[3]);
        *(u32x2*)((char*)Ws + wswr[m][ct]) = pk;           // wave-private rows
      }
    }
    // PV with normalized P (same-wave Ws dep; lgkmcnt handled by compiler)
#pragma unroll
    for (int jc = 0; jc < 2; ++jc) {
      const bf16x8 pa0 = *(const bf16x8*)((const char*)Ws + wsrd[0][jc]);
      const bf16x8 pa1 = *(const bf16x8*)((const char*)Ws + wsrd[1][jc]);
#pragma unroll
      for (int dt = 0; dt < 4; ++dt) {
        const bf16x8 vf = *(const bf16x8*)((const char*)Vb[cur] + voff[jc][dt]);
        pv[0][dt] = __builtin_amdgcn_mfma_f32_16x16x32_bf16(pa0, vf, pv[0][dt], 0, 0, 0);
        pv[1][dt] = __builtin_amdgcn_mfma_f32_16x16x32_bf16(pa1, vf, pv[1][dt], 0, 0, 0);
      }
    }
    if (t < 31) {
      // retire exactly this wave's 8 glds (oldest); 8 AW stores keep flying
      asm volatile("s_waitcnt vmcnt(8) lgkmcnt(0)" ::: "memory");
      __builtin_amdgcn_sched_barrier(0);
      __builtin_amdgcn_s_barrier();
    }
    cur ^= 1;
  }

  // XB epilogue: PV already normalized
#pragma unroll
  for (int m = 0; m < 2; ++m)
#pragma unroll
    for (int dt = 0; dt < 4; ++dt)
#pragma unroll
      for (int r = 0; r < 4; ++r) {
        const int row = b * kS + i0 + wv * 32 + m * 16 + lg * 4 + r;  // (b,i)
        const int col = n * 64 + dt * 16 + l15;                       // (n d)
        XB[(size_t)row * kH + col] = f2bf(pv[m][dt][r]);
      }
}

// ---------------------------------------------------------------------------
extern "C" void kernel_launch(void* const* d_in, const int* in_sizes, int n_in,
                              void* d_out, int out_size, void* d_ws, size_t ws_size,
                              hipStream_t stream) {
  const float* q  = (const float*)d_in[0];
  const float* k  = (const float*)d_in[1];
  const float* v  = (const float*)d_in[2];
  const float* Wq = (const float*)d_in[3];
  const float* Wk = (const float*)d_in[4];
  const float* Wv = (const float*)d_in[5];
  const float* Wo = (const float*)d_in[6];

  float* out = (float*)d_out;
  float* aw  = out + (size_t)kBS * kH;
  float* rsb = out;   // row sums stashed in out; final GEMM overwrites

  unsigned short* QP  = (unsigned short*)d_ws;         // 8 MB
  unsigned short* KP  = QP  + (size_t)kBS * kH;        // 8 MB
  unsigned short* VPT = KP  + (size_t)kBS * kH;        // 8 MB
  unsigned short* XB  = VPT + (size_t)kBS * kH;        // 8 MB (total 32 MB)

  // bf16 stash in AW region: consumed by proj (disp 2) before attn writes AW
  unsigned short* stash = (unsigned short*)aw;
  unsigned short* QB  = stash;
  unsigned short* KB  = stash + (size_t)4194304;
  unsigned short* VB  = stash + (size_t)8388608;
  unsigned short* Wqb = stash + (size_t)12582912;
  unsigned short* Wkb = stash + (size_t)13631488;
  unsigned short* Wvb = stash + (size_t)14680064;

  cvt_all<<<dim3(2560, 3), 256, 0, stream>>>(q, k, v, Wq, Wk, Wv, stash);
  gemm_k<true><<<dim3(8, 32, 3), 256, 0, stream>>>(QB, KB, VB, Wqb, Wkb, Wvb, QP, KP, VPT);
  attn_rs<<<dim3(1024), 128, 0, stream>>>(QP, KP, rsb);
  attn_main<<<dim3(1024), 128, 0, stream>>>(QP, KP, VPT, rsb, aw, XB);
  gemm_k<false><<<dim3(8, 32, 1), 256, 0, stream>>>(XB, XB, XB, Wo, Wo, Wo, out, out, out);
}

// Round 9
// 280.706 us; speedup vs baseline: 1.1930x; 1.1930x over previous
//
#include <hip/hip_runtime.h>
#include <hip/hip_bf16.h>

#define DEVI __device__ __forceinline__

constexpr int kS  = 2048;
constexpr int kH  = 1024;
constexpr int kD  = 64;
constexpr int kBS = 4096;            // B*S
constexpr int kHeadEls = kS * kD;    // elements per (b,head) chunk

typedef __attribute__((ext_vector_type(4))) float f32x4;
typedef __attribute__((ext_vector_type(8))) __bf16 bf16x8;
typedef __attribute__((ext_vector_type(8))) unsigned short u16x8;
typedef __attribute__((ext_vector_type(2))) unsigned int u32x2;

DEVI unsigned short f2bf(float f) {            // RNE fp32 -> bf16
  unsigned int u = __builtin_bit_cast(unsigned int, f);
  u = u + 0x7FFFu + ((u >> 16) & 1u);
  return (unsigned short)(u >> 16);
}
DEVI float fast_exp2(float x) { float r; asm("v_exp_f32 %0, %1" : "=v"(r) : "v"(x)); return r; }
DEVI unsigned int cvt_pk(float lo, float hi) {
  unsigned int r; asm("v_cvt_pk_bf16_f32 %0, %1, %2" : "=v"(r) : "v"(lo), "v"(hi)); return r;
}
DEVI bf16x8 cvt8(const f32x4 a, const f32x4 b) {
  union { unsigned int u[4]; bf16x8 v; } r;
  r.u[0] = cvt_pk(a[0], a[1]); r.u[1] = cvt_pk(a[2], a[3]);
  r.u[2] = cvt_pk(b[0], b[1]); r.u[3] = cvt_pk(b[2], b[3]);
  return r.v;
}
DEVI float bf2f(unsigned int lo16) {           // bf16 (low 16 bits) -> f32
  return __builtin_bit_cast(float, lo16 << 16);
}

#define GLDS16(g, l) __builtin_amdgcn_global_load_lds( \
    (const __attribute__((address_space(1))) void*)(g), \
    (__attribute__((address_space(3))) void*)(l), 16, 0, 0)

// ---------------------------------------------------------------------------
// fp32 -> bf16 weight pre-convert (Wq, Wk, Wv), 1M elements each.
// ---------------------------------------------------------------------------
__global__ __launch_bounds__(256) void cvt_w(
    const float* __restrict__ s0, const float* __restrict__ s1, const float* __restrict__ s2,
    unsigned short* __restrict__ d0, unsigned short* __restrict__ d1, unsigned short* __restrict__ d2)
{
  const int m = blockIdx.y;
  const float* s = m == 0 ? s0 : m == 1 ? s1 : s2;
  unsigned short* d = m == 0 ? d0 : m == 1 ? d1 : d2;
  const int i = (blockIdx.x * 256 + threadIdx.x) * 8;
  f32x4 a = *(const f32x4*)(s + i);
  f32x4 b = *(const f32x4*)(s + i + 4);
  union { unsigned int u[4]; u16x8 v; } r;
  r.u[0] = cvt_pk(a[0], a[1]); r.u[1] = cvt_pk(a[2], a[3]);
  r.u[2] = cvt_pk(b[0], b[1]); r.u[3] = cvt_pk(b[2], b[3]);
  *(u16x8*)(d + i) = r.v;
}

// ---------------------------------------------------------------------------
// GEMM: C[m,n] = sum_k A[m,k]*B[n,k]  (C = A @ B^T), M=4096 N=1024 K=1024.
// 2-phase double-buffered global_load_lds staging.
// PROJ:  A fp32 (q/k/v, cvt inline), B bf16 (pre-cvt W), C bf16
//        (z==2 -> transposed VPT layout). LDS 48 KB -> 3 blocks/CU.
// !PROJ: A bf16 (XB), B fp32 (Wo, cvt inline), C fp32 nontemporal.
// ---------------------------------------------------------------------------
template<bool PROJ>
__global__ __launch_bounds__(256, 3) void gemm_k(
    const void* __restrict__ Aq, const void* __restrict__ Ak, const void* __restrict__ Av,
    const void* __restrict__ Bq, const void* __restrict__ Bk, const void* __restrict__ Bv,
    void* __restrict__ Cq, void* __restrict__ Ck, void* __restrict__ Cv)
{
  constexpr int K = kH;
  __shared__ __align__(16) unsigned char As[2][PROJ ? 16384 : 8192];
  __shared__ __align__(16) unsigned char Bs[2][PROJ ? 8192 : 16384];

  const int z = PROJ ? blockIdx.z : 0;
  const void* Ap = z == 0 ? Aq : z == 1 ? Ak : Av;
  const void* Bp = z == 0 ? Bq : z == 1 ? Bk : Bv;
  void*       Cp = z == 0 ? Cq : z == 1 ? Ck : Cv;

  const int tid  = threadIdx.x;
  const int lane = tid & 63, wv = tid >> 6;
  const int l15  = lane & 15, lg = lane >> 4;
  const int m0 = blockIdx.y * 128, n0 = blockIdx.x * 128;
  const int wM = (wv & 1) * 64, wN = (wv >> 1) * 64;

  // staging sources (pre-swizzled; fp32: byte^=(row&7)<<4, bf16: byte^=((row>>1)&3)<<4)
  const char* aSrc[PROJ ? 4 : 2];
  if constexpr (PROJ) {
#pragma unroll
    for (int c = 0; c < 4; ++c) {
      const int row = c * 32 + wv * 8 + (lane >> 3);
      const int cb  = ((lane & 7) * 16) ^ ((row & 7) << 4);
      aSrc[c] = (const char*)Ap + ((size_t)(m0 + row) * K) * 4 + cb;
    }
  } else {
#pragma unroll
    for (int c = 0; c < 2; ++c) {
      const int row = c * 64 + (tid >> 2);
      const int cb  = ((tid & 3) * 16) ^ (((row >> 1) & 3) << 4);
      aSrc[c] = (const char*)Ap + ((size_t)(m0 + row) * K) * 2 + cb;
    }
  }
  const char* bSrc[PROJ ? 2 : 4];
  if constexpr (PROJ) {
#pragma unroll
    for (int c = 0; c < 2; ++c) {
      const int row = c * 64 + (tid >> 2);
      const int cb  = ((tid & 3) * 16) ^ (((row >> 1) & 3) << 4);
      bSrc[c] = (const char*)Bp + ((size_t)(n0 + row) * K) * 2 + cb;
    }
  } else {
#pragma unroll
    for (int c = 0; c < 4; ++c) {
      const int row = c * 32 + wv * 8 + (lane >> 3);
      const int cb  = ((lane & 7) * 16) ^ ((row & 7) << 4);
      bSrc[c] = (const char*)Bp + ((size_t)(n0 + row) * K) * 4 + cb;
    }
  }

  int aoff[4], boff[4];
#pragma unroll
  for (int t = 0; t < 4; ++t) {
    const int rA = wM + t * 16 + l15;
    aoff[t] = PROJ ? (rA * 128 + ((lg * 32) ^ ((rA & 7) << 4)))
                   : (rA * 64  + ((lg * 16) ^ (((rA >> 1) & 3) << 4)));
    const int rB = wN + t * 16 + l15;
    boff[t] = PROJ ? (rB * 64  + ((lg * 16) ^ (((rB >> 1) & 3) << 4)))
                   : (rB * 128 + ((lg * 32) ^ ((rB & 7) << 4)));
  }

  f32x4 acc[4][4];
#pragma unroll
  for (int i = 0; i < 4; ++i)
#pragma unroll
    for (int j = 0; j < 4; ++j) acc[i][j] = {0.f, 0.f, 0.f, 0.f};

  auto STG = [&](int kk, int bb) {
    if constexpr (PROJ) {
#pragma unroll
      for (int c = 0; c < 4; ++c)
        GLDS16(aSrc[c] + (size_t)kk * 4, &As[bb][c * 4096 + wv * 1024]);
#pragma unroll
      for (int c = 0; c < 2; ++c)
        GLDS16(bSrc[c] + (size_t)kk * 2, &Bs[bb][c * 4096 + wv * 1024]);
    } else {
#pragma unroll
      for (int c = 0; c < 2; ++c)
        GLDS16(aSrc[c] + (size_t)kk * 2, &As[bb][c * 4096 + wv * 1024]);
#pragma unroll
      for (int c = 0; c < 4; ++c)
        GLDS16(bSrc[c] + (size_t)kk * 4, &Bs[bb][c * 4096 + wv * 1024]);
    }
  };

  STG(0, 0);
  __syncthreads();
  int cur = 0;
  for (int t = 0; t < K / 32; ++t) {
    if (t < K / 32 - 1) STG((t + 1) * 32, cur ^ 1);
    bf16x8 af[4], bfr[4];
#pragma unroll
    for (int x = 0; x < 4; ++x) {
      if constexpr (PROJ) {
        f32x4 p0 = *(const f32x4*)&As[cur][aoff[x]];
        f32x4 p1 = *(const f32x4*)&As[cur][aoff[x] ^ 16];
        af[x] = cvt8(p0, p1);
        bfr[x] = *(const bf16x8*)&Bs[cur][boff[x]];
      } else {
        af[x] = *(const bf16x8*)&As[cur][aoff[x]];
        f32x4 q0 = *(const f32x4*)&Bs[cur][boff[x]];
        f32x4 q1 = *(const f32x4*)&Bs[cur][boff[x] ^ 16];
        bfr[x] = cvt8(q0, q1);
      }
    }
#pragma unroll
    for (int mt = 0; mt < 4; ++mt)
#pragma unroll
      for (int nt = 0; nt < 4; ++nt)
        acc[mt][nt] = __builtin_amdgcn_mfma_f32_16x16x32_bf16(af[mt], bfr[nt], acc[mt][nt], 0, 0, 0);
    __syncthreads();   // drains next-tile staging (in flight during compute)
    cur ^= 1;
  }

  if constexpr (PROJ) {
    const bool vmode = (z == 2);
#pragma unroll
    for (int mt = 0; mt < 4; ++mt)
#pragma unroll
      for (int nt = 0; nt < 4; ++nt)
#pragma unroll
        for (int r = 0; r < 4; ++r) {
          const int row = m0 + wM + mt * 16 + lg * 4 + r;
          const int col = n0 + wN + nt * 16 + l15;
          const unsigned short hv = f2bf(acc[mt][nt][r]);
          if (!vmode) {
            ((unsigned short*)Cp)[(size_t)row * kH + col] = hv;
          } else {
            const int bn = row >> 7;                       // VPT[bn][d][j]
            const int j  = ((row & 127) << 4) | (col >> 6);
            const int d  = col & 63;
            ((unsigned short*)Cp)[(size_t)bn * kHeadEls + (size_t)d * kS + j] = hv;
          }
        }
  } else {
#pragma unroll
    for (int mt = 0; mt < 4; ++mt)
#pragma unroll
      for (int nt = 0; nt < 4; ++nt)
#pragma unroll
        for (int r = 0; r < 4; ++r) {
          const int row = m0 + wM + mt * 16 + lg * 4 + r;
          const int col = n0 + wN + nt * 16 + l15;
          __builtin_nontemporal_store(acc[mt][nt][r], (float*)Cp + (size_t)row * kH + col);
        }
  }
}

// ---------------------------------------------------------------------------
// attn_rs: row sums only (unchanged from round 8, proven).
// ---------------------------------------------------------------------------
__global__ __launch_bounds__(128, 2) void attn_rs(
    const unsigned short* __restrict__ QP,
    const unsigned short* __restrict__ KP,
    float* __restrict__ rsout)          // [32][2048]
{
  __shared__ __align__(16) unsigned short Kb[2][4096];

  const int tid  = threadIdx.x;
  const int lane = tid & 63, wv = tid >> 6;
  const int l15  = lane & 15, lg = lane >> 4;
  const int f = blockIdx.x;
  const int x = f & 7, r8 = f >> 3;
  const int bn = (r8 >> 5) * 8 + x;     // 4 heads per XCD
  const int i0 = (r8 & 31) * 64;

  const char* Khb = (const char*)(KP + (size_t)bn * kHeadEls);
  const unsigned short* Qh = QP + (size_t)bn * kHeadEls;

  const int srw = tid >> 3, scl = (tid & 7) * 16;
  const int kbase = srw * 128 + (scl ^ ((srw & 7) << 4));

  auto STAGE = [&](int j0, int bb) {
#pragma unroll
    for (int p = 0; p < 4; ++p)
      GLDS16(Khb + (size_t)j0 * 128 + kbase + p * 2048, (char*)Kb[bb] + p * 2048 + tid * 16);
  };

  int koff[4][2];
#pragma unroll
  for (int ct = 0; ct < 4; ++ct) {
    const int rK = ct * 16 + l15;
#pragma unroll
    for (int h = 0; h < 2; ++h)
      koff[ct][h] = rK * 128 + ((h * 64 + lg * 16) ^ ((rK & 7) << 4));
  }

  bf16x8 qf[2][2];
#pragma unroll
  for (int m = 0; m < 2; ++m) {
    const int qr = i0 + wv * 32 + m * 16 + l15;
#pragma unroll
    for (int h = 0; h < 2; ++h)
      qf[m][h] = *(const bf16x8*)(Qh + (size_t)qr * kD + h * 32 + lg * 8);
  }
  const float cexp = 0.18033688011112042f;   // log2(e)/8

  float rs[2] = {0.f, 0.f};
  STAGE(0, 0);
  __syncthreads();
  int cur = 0;
  for (int t = 0; t < 32; ++t) {
    if (t < 31) STAGE((t + 1) * 64, cur ^ 1);
#pragma unroll
    for (int ct = 0; ct < 4; ++ct) {
      const bf16x8 kb0 = *(const bf16x8*)((const char*)Kb[cur] + koff[ct][0]);
      const bf16x8 kb1 = *(const bf16x8*)((const char*)Kb[cur] + koff[ct][1]);
#pragma unroll
      for (int m = 0; m < 2; ++m) {
        f32x4 s = {0.f, 0.f, 0.f, 0.f};
        s = __builtin_amdgcn_mfma_f32_16x16x32_bf16(kb0, qf[m][0], s, 0, 0, 0);
        s = __builtin_amdgcn_mfma_f32_16x16x32_bf16(kb1, qf[m][1], s, 0, 0, 0);
        const float w0 = fast_exp2(s[0] * cexp), w1 = fast_exp2(s[1] * cexp);
        const float w2 = fast_exp2(s[2] * cexp), w3 = fast_exp2(s[3] * cexp);
        rs[m] += (w0 + w1) + (w2 + w3);
      }
    }
    __syncthreads();
    cur ^= 1;
  }
#pragma unroll
  for (int m = 0; m < 2; ++m) {
    rs[m] += __shfl_xor(rs[m], 16, 64);
    rs[m] += __shfl_xor(rs[m], 32, 64);
  }
  if (lg == 0) {
#pragma unroll
    for (int m = 0; m < 2; ++m)
      rsout[(size_t)bn * kS + i0 + wv * 32 + m * 16 + l15] = rs[m];
  }
}

// ---------------------------------------------------------------------------
// attn_main: QK^T once -> normalized w -> Ws (bf16) -> PV, and AW stores go
// through Ws readback: lane reads 4 consecutive j of one row (ds_read_b64),
// expands bf16->f32, stores 4 rows x 256B = 8 FULL 128B lines per instr
// (fillBuffer's transaction profile; old path was 16 half-lines per instr).
// Counted vmcnt(8) + raw s_barrier keeps stores flying across tiles.
// ---------------------------------------------------------------------------
__global__ __launch_bounds__(128, 2) void attn_main(
    const unsigned short* __restrict__ QP,
    const unsigned short* __restrict__ KP,
    const unsigned short* __restrict__ VPT,
    const float* __restrict__ rsb,      // [32][2048]
    float* __restrict__ AW,             // [32][2048][2048] fp32
    unsigned short* __restrict__ XB)    // [4096][1024] bf16
{
  __shared__ __align__(16) unsigned short Kb[2][4096];   // [64 j][64 d] swz
  __shared__ __align__(16) unsigned short Vb[2][4096];   // [64 d][64 j] swz
  __shared__ __align__(16) unsigned short Ws[4096];      // [64 q][64 j] swz

  const int tid  = threadIdx.x;
  const int lane = tid & 63, wv = tid >> 6;
  const int l15  = lane & 15, lg = lane >> 4;
  const int f = blockIdx.x;
  const int x = f & 7, r8 = f >> 3;
  const int bn = (r8 >> 5) * 8 + x;     // 4 heads per XCD
  const int i0 = (r8 & 31) * 64;
  const int b = bn >> 4, n = bn & 15;

  const char* Khb = (const char*)(KP + (size_t)bn * kHeadEls);
  const char* Vhb = (const char*)(VPT + (size_t)bn * kHeadEls);
  const unsigned short* Qh = QP + (size_t)bn * kHeadEls;

  const int srw = tid >> 3, scl = (tid & 7) * 16;
  const int sswz = scl ^ ((srw & 7) << 4);
  const int kbase = srw * 128 + sswz;
  const int vbase = srw * 4096 + sswz;

  auto STAGE_KV = [&](int j0, int bb) {
#pragma unroll
    for (int p = 0; p < 4; ++p) {
      GLDS16(Khb + (size_t)j0 * 128 + kbase + p * 2048,
             (char*)Kb[bb] + p * 2048 + tid * 16);
      GLDS16(Vhb + (size_t)j0 * 2 + vbase + (size_t)p * 65536,
             (char*)Vb[bb] + p * 2048 + tid * 16);
    }
  };

  int koff[4][2], voff[2][4], wswr[2][4], wsrd[2][2];
#pragma unroll
  for (int ct = 0; ct < 4; ++ct) {
    const int rK = ct * 16 + l15;
#pragma unroll
    for (int h = 0; h < 2; ++h)
      koff[ct][h] = rK * 128 + ((h * 64 + lg * 16) ^ ((rK & 7) << 4));
  }
#pragma unroll
  for (int jc = 0; jc < 2; ++jc)
#pragma unroll
    for (int dt = 0; dt < 4; ++dt) {
      const int d = dt * 16 + l15;
      voff[jc][dt] = d * 128 + ((jc * 64 + lg * 16) ^ ((d & 7) << 4));
    }
#pragma unroll
  for (int m = 0; m < 2; ++m) {
    const int rw = wv * 32 + m * 16 + l15;
#pragma unroll
    for (int ct = 0; ct < 4; ++ct)
      wswr[m][ct] = rw * 128 + ((ct * 32 + lg * 8) ^ ((rw & 7) << 4));
#pragma unroll
    for (int jc = 0; jc < 2; ++jc)
      wsrd[m][jc] = rw * 128 + ((jc * 64 + lg * 16) ^ ((rw & 7) << 4));
  }

  // AW contiguous-store descriptors: instr u covers rows wv*32+u*4+lg,
  // lane l15 handles 4 consecutive j (16B f32) at j = l15*4.
  int awrd[8];
  float* awp[8];
#pragma unroll
  for (int u = 0; u < 8; ++u) {
    const int rw = wv * 32 + u * 4 + lg;
    awrd[u] = rw * 128 + ((l15 * 8) ^ ((rw & 7) << 4));
    awp[u]  = AW + ((size_t)bn * kS + i0 + rw) * kS + l15 * 4;
  }

  bf16x8 qf[2][2];
  float inv[2];
#pragma unroll
  for (int m = 0; m < 2; ++m) {
    const int qr = i0 + wv * 32 + m * 16 + l15;
#pragma unroll
    for (int h = 0; h < 2; ++h)
      qf[m][h] = *(const bf16x8*)(Qh + (size_t)qr * kD + h * 32 + lg * 8);
    inv[m] = 1.0f / rsb[(size_t)bn * kS + qr];
  }
  const float cexp = 0.18033688011112042f;   // log2(e)/8

  f32x4 pv[2][4];
#pragma unroll
  for (int m = 0; m < 2; ++m)
#pragma unroll
    for (int dt = 0; dt < 4; ++dt) pv[m][dt] = {0.f, 0.f, 0.f, 0.f};

  STAGE_KV(0, 0);
  asm volatile("s_waitcnt vmcnt(0) lgkmcnt(0)" ::: "memory");
  __builtin_amdgcn_sched_barrier(0);
  __builtin_amdgcn_s_barrier();

  int cur = 0;
  for (int t = 0; t < 32; ++t) {
    if (t < 31) STAGE_KV((t + 1) * 64, cur ^ 1);   // 8 glds, oldest in queue
    __builtin_amdgcn_sched_barrier(0);             // pin glds before AW stores
    // QK^T (swapped) -> normalized w -> Ws write (bf16)
#pragma unroll
    for (int ct = 0; ct < 4; ++ct) {
      const bf16x8 kb0 = *(const bf16x8*)((const char*)Kb[cur] + koff[ct][0]);
      const bf16x8 kb1 = *(const bf16x8*)((const char*)Kb[cur] + koff[ct][1]);
#pragma unroll
      for (int m = 0; m < 2; ++m) {
        f32x4 s = {0.f, 0.f, 0.f, 0.f};
        s = __builtin_amdgcn_mfma_f32_16x16x32_bf16(kb0, qf[m][0], s, 0, 0, 0);
        s = __builtin_amdgcn_mfma_f32_16x16x32_bf16(kb1, qf[m][1], s, 0, 0, 0);
        f32x4 w;
#pragma unroll
        for (int r = 0; r < 4; ++r) w[r] = fast_exp2(s[r] * cexp) * inv[m];
        u32x2 pk; pk[0] = cvt_pk(w[0], w[1]); pk[1] = cvt_pk(w[2], w[3]);
        *(u32x2*)((char*)Ws + wswr[m][ct]) = pk;   // wave-private rows
      }
    }
    // PV (same-wave Ws dep)
#pragma unroll
    for (int jc = 0; jc < 2; ++jc) {
      const bf16x8 pa0 = *(const bf16x8*)((const char*)Ws + wsrd[0][jc]);
      const bf16x8 pa1 = *(const bf16x8*)((const char*)Ws + wsrd[1][jc]);
#pragma unroll
      for (int dt = 0; dt < 4; ++dt) {
        const bf16x8 vf = *(const bf16x8*)((const char*)Vb[cur] + voff[jc][dt]);
        pv[0][dt] = __builtin_amdgcn_mfma_f32_16x16x32_bf16(pa0, vf, pv[0][dt], 0, 0, 0);
        pv[1][dt] = __builtin_amdgcn_mfma_f32_16x16x32_bf16(pa1, vf, pv[1][dt], 0, 0, 0);
      }
    }
    // AW stores: Ws readback row-contiguous -> 8 full-line 1KB store instrs
#pragma unroll
    for (int u = 0; u < 8; ++u) {
      const u32x2 pk = *(const u32x2*)((const char*)Ws + awrd[u]);
      f32x4 w;
      w[0] = bf2f(pk[0] & 0xFFFFu);
      w[1] = bf2f(pk[0] >> 16);
      w[2] = bf2f(pk[1] & 0xFFFFu);
      w[3] = bf2f(pk[1] >> 16);
      __builtin_nontemporal_store(w, (f32x4*)(awp[u] + t * 64));
    }
    if (t < 31) {
      // retire exactly this wave's 8 glds (oldest); 8 AW stores keep flying
      asm volatile("s_waitcnt vmcnt(8) lgkmcnt(0)" ::: "memory");
      __builtin_amdgcn_sched_barrier(0);
      __builtin_amdgcn_s_barrier();
    }
    cur ^= 1;
  }

  // XB epilogue: PV already normalized
#pragma unroll
  for (int m = 0; m < 2; ++m)
#pragma unroll
    for (int dt = 0; dt < 4; ++dt)
#pragma unroll
      for (int r = 0; r < 4; ++r) {
        const int row = b * kS + i0 + wv * 32 + m * 16 + lg * 4 + r;  // (b,i)
        const int col = n * 64 + dt * 16 + l15;                       // (n d)
        XB[(size_t)row * kH + col] = f2bf(pv[m][dt][r]);
      }
}

// ---------------------------------------------------------------------------
extern "C" void kernel_launch(void* const* d_in, const int* in_sizes, int n_in,
                              void* d_out, int out_size, void* d_ws, size_t ws_size,
                              hipStream_t stream) {
  const float* q  = (const float*)d_in[0];
  const float* k  = (const float*)d_in[1];
  const float* v  = (const float*)d_in[2];
  const float* Wq = (const float*)d_in[3];
  const float* Wk = (const float*)d_in[4];
  const float* Wv = (const float*)d_in[5];
  const float* Wo = (const float*)d_in[6];

  float* out = (float*)d_out;
  float* aw  = out + (size_t)kBS * kH;
  float* rsb = out;   // row sums stashed in out; final GEMM overwrites

  unsigned short* QP  = (unsigned short*)d_ws;         // 8 MB
  unsigned short* KP  = QP  + (size_t)kBS * kH;        // 8 MB
  unsigned short* VPT = KP  + (size_t)kBS * kH;        // 8 MB
  unsigned short* XB  = VPT + (size_t)kBS * kH;        // 8 MB (total 32 MB)

  // bf16 W copies in AW region: consumed by proj before attn writes AW
  unsigned short* stash = (unsigned short*)aw;
  unsigned short* Wqb = stash;
  unsigned short* Wkb = stash + (size_t)kH * kH;
  unsigned short* Wvb = stash + (size_t)2 * kH * kH;

  cvt_w<<<dim3(512, 3), 256, 0, stream>>>(Wq, Wk, Wv, Wqb, Wkb, Wvb);
  gemm_k<true><<<dim3(8, 32, 3), 256, 0, stream>>>(q, k, v, Wqb, Wkb, Wvb, QP, KP, VPT);
  attn_rs<<<dim3(1024), 128, 0, stream>>>(QP, KP, rsb);
  attn_main<<<dim3(1024), 128, 0, stream>>>(QP, KP, VPT, rsb, aw, XB);
  gemm_k<false><<<dim3(8, 32, 1), 256, 0, stream>>>(XB, XB, XB, Wo, Wo, Wo, out, out, out);
}

// Round 10
// 261.134 us; speedup vs baseline: 1.2824x; 1.0750x over previous
//
#include <hip/hip_runtime.h>
#include <hip/hip_bf16.h>

#define DEVI __device__ __forceinline__

constexpr int kS  = 2048;
constexpr int kH  = 1024;
constexpr int kD  = 64;
constexpr int kBS = 4096;            // B*S
constexpr int kHeadEls = kS * kD;    // elements per (b,head) chunk

typedef __attribute__((ext_vector_type(4))) float f32x4;
typedef __attribute__((ext_vector_type(8))) __bf16 bf16x8;
typedef __attribute__((ext_vector_type(8))) unsigned short u16x8;
typedef __attribute__((ext_vector_type(2))) unsigned int u32x2;

DEVI unsigned short f2bf(float f) {            // RNE fp32 -> bf16
  unsigned int u = __builtin_bit_cast(unsigned int, f);
  u = u + 0x7FFFu + ((u >> 16) & 1u);
  return (unsigned short)(u >> 16);
}
DEVI float fast_exp2(float x) { float r; asm("v_exp_f32 %0, %1" : "=v"(r) : "v"(x)); return r; }
DEVI unsigned int cvt_pk(float lo, float hi) {
  unsigned int r; asm("v_cvt_pk_bf16_f32 %0, %1, %2" : "=v"(r) : "v"(lo), "v"(hi)); return r;
}
DEVI bf16x8 cvt8(const f32x4 a, const f32x4 b) {
  union { unsigned int u[4]; bf16x8 v; } r;
  r.u[0] = cvt_pk(a[0], a[1]); r.u[1] = cvt_pk(a[2], a[3]);
  r.u[2] = cvt_pk(b[0], b[1]); r.u[3] = cvt_pk(b[2], b[3]);
  return r.v;
}
DEVI float bf2f(unsigned int lo16) {           // bf16 (low 16 bits) -> f32
  return __builtin_bit_cast(float, lo16 << 16);
}

#define GLDS16(g, l) __builtin_amdgcn_global_load_lds( \
    (const __attribute__((address_space(1))) void*)(g), \
    (__attribute__((address_space(3))) void*)(l), 16, 0, 0)

// ---------------------------------------------------------------------------
// fp32 -> bf16 weight pre-convert (Wq, Wk, Wv), 1M elements each.
// ---------------------------------------------------------------------------
__global__ __launch_bounds__(256) void cvt_w(
    const float* __restrict__ s0, const float* __restrict__ s1, const float* __restrict__ s2,
    unsigned short* __restrict__ d0, unsigned short* __restrict__ d1, unsigned short* __restrict__ d2)
{
  const int m = blockIdx.y;
  const float* s = m == 0 ? s0 : m == 1 ? s1 : s2;
  unsigned short* d = m == 0 ? d0 : m == 1 ? d1 : d2;
  const int i = (blockIdx.x * 256 + threadIdx.x) * 8;
  f32x4 a = *(const f32x4*)(s + i);
  f32x4 b = *(const f32x4*)(s + i + 4);
  union { unsigned int u[4]; u16x8 v; } r;
  r.u[0] = cvt_pk(a[0], a[1]); r.u[1] = cvt_pk(a[2], a[3]);
  r.u[2] = cvt_pk(b[0], b[1]); r.u[3] = cvt_pk(b[2], b[3]);
  *(u16x8*)(d + i) = r.v;
}

// ---------------------------------------------------------------------------
// Projection GEMM (unchanged from round 9, proven): C = A @ B^T.
// A fp32 (q/k/v, cvt inline), B bf16 (pre-cvt W), C bf16; z==2 -> VPT layout.
// ---------------------------------------------------------------------------
__global__ __launch_bounds__(256, 3) void gemm_p(
    const void* __restrict__ Aq, const void* __restrict__ Ak, const void* __restrict__ Av,
    const void* __restrict__ Bq, const void* __restrict__ Bk, const void* __restrict__ Bv,
    void* __restrict__ Cq, void* __restrict__ Ck, void* __restrict__ Cv)
{
  constexpr int K = kH;
  __shared__ __align__(16) unsigned char As[2][16384];
  __shared__ __align__(16) unsigned char Bs[2][8192];

  const int z = blockIdx.z;
  const void* Ap = z == 0 ? Aq : z == 1 ? Ak : Av;
  const void* Bp = z == 0 ? Bq : z == 1 ? Bk : Bv;
  void*       Cp = z == 0 ? Cq : z == 1 ? Ck : Cv;

  const int tid  = threadIdx.x;
  const int lane = tid & 63, wv = tid >> 6;
  const int l15  = lane & 15, lg = lane >> 4;
  const int m0 = blockIdx.y * 128, n0 = blockIdx.x * 128;
  const int wM = (wv & 1) * 64, wN = (wv >> 1) * 64;

  const char* aSrc[4];
#pragma unroll
  for (int c = 0; c < 4; ++c) {
    const int row = c * 32 + wv * 8 + (lane >> 3);
    const int cb  = ((lane & 7) * 16) ^ ((row & 7) << 4);
    aSrc[c] = (const char*)Ap + ((size_t)(m0 + row) * K) * 4 + cb;
  }
  const char* bSrc[2];
#pragma unroll
  for (int c = 0; c < 2; ++c) {
    const int row = c * 64 + (tid >> 2);
    const int cb  = ((tid & 3) * 16) ^ (((row >> 1) & 3) << 4);
    bSrc[c] = (const char*)Bp + ((size_t)(n0 + row) * K) * 2 + cb;
  }

  int aoff[4], boff[4];
#pragma unroll
  for (int t = 0; t < 4; ++t) {
    const int rA = wM + t * 16 + l15;
    aoff[t] = rA * 128 + ((lg * 32) ^ ((rA & 7) << 4));
    const int rB = wN + t * 16 + l15;
    boff[t] = rB * 64 + ((lg * 16) ^ (((rB >> 1) & 3) << 4));
  }

  f32x4 acc[4][4];
#pragma unroll
  for (int i = 0; i < 4; ++i)
#pragma unroll
    for (int j = 0; j < 4; ++j) acc[i][j] = {0.f, 0.f, 0.f, 0.f};

  auto STG = [&](int kk, int bb) {
#pragma unroll
    for (int c = 0; c < 4; ++c)
      GLDS16(aSrc[c] + (size_t)kk * 4, &As[bb][c * 4096 + wv * 1024]);
#pragma unroll
    for (int c = 0; c < 2; ++c)
      GLDS16(bSrc[c] + (size_t)kk * 2, &Bs[bb][c * 4096 + wv * 1024]);
  };

  STG(0, 0);
  __syncthreads();
  int cur = 0;
  for (int t = 0; t < K / 32; ++t) {
    if (t < K / 32 - 1) STG((t + 1) * 32, cur ^ 1);
    bf16x8 af[4], bfr[4];
#pragma unroll
    for (int x = 0; x < 4; ++x) {
      f32x4 p0 = *(const f32x4*)&As[cur][aoff[x]];
      f32x4 p1 = *(const f32x4*)&As[cur][aoff[x] ^ 16];
      af[x] = cvt8(p0, p1);
      bfr[x] = *(const bf16x8*)&Bs[cur][boff[x]];
    }
#pragma unroll
    for (int mt = 0; mt < 4; ++mt)
#pragma unroll
      for (int nt = 0; nt < 4; ++nt)
        acc[mt][nt] = __builtin_amdgcn_mfma_f32_16x16x32_bf16(af[mt], bfr[nt], acc[mt][nt], 0, 0, 0);
    __syncthreads();
    cur ^= 1;
  }

  const bool vmode = (z == 2);
#pragma unroll
  for (int mt = 0; mt < 4; ++mt)
#pragma unroll
    for (int nt = 0; nt < 4; ++nt)
#pragma unroll
      for (int r = 0; r < 4; ++r) {
        const int row = m0 + wM + mt * 16 + lg * 4 + r;
        const int col = n0 + wN + nt * 16 + l15;
        const unsigned short hv = f2bf(acc[mt][nt][r]);
        if (!vmode) {
          ((unsigned short*)Cp)[(size_t)row * kH + col] = hv;
        } else {
          const int bn = row >> 7;                       // VPT[bn][d][j]
          const int j  = ((row & 127) << 4) | (col >> 6);
          const int d  = col & 63;
          ((unsigned short*)Cp)[(size_t)bn * kHeadEls + (size_t)d * kS + j] = hv;
        }
      }
}

// ---------------------------------------------------------------------------
// Final GEMM: out = XB @ Wo^T, tile 128x64 -> grid (16,32)=512 blocks (2/CU).
// A bf16 (XB), B fp32 (Wo, cvt inline), C fp32 nontemporal. LDS 32 KB.
// ---------------------------------------------------------------------------
__global__ __launch_bounds__(256, 3) void gemm_f(
    const unsigned short* __restrict__ Ap, const float* __restrict__ Bp,
    float* __restrict__ Cp)
{
  constexpr int K = kH;
  __shared__ __align__(16) unsigned char As[2][8192];
  __shared__ __align__(16) unsigned char Bs[2][8192];

  const int tid  = threadIdx.x;
  const int lane = tid & 63, wv = tid >> 6;
  const int l15  = lane & 15, lg = lane >> 4;
  const int m0 = blockIdx.y * 128, n0 = blockIdx.x * 64;
  const int wM = (wv & 1) * 64, wN = (wv >> 1) * 32;

  const char* aSrc[2];
#pragma unroll
  for (int c = 0; c < 2; ++c) {
    const int row = c * 64 + (tid >> 2);
    const int cb  = ((tid & 3) * 16) ^ (((row >> 1) & 3) << 4);
    aSrc[c] = (const char*)Ap + ((size_t)(m0 + row) * K) * 2 + cb;
  }
  const char* bSrc[2];
#pragma unroll
  for (int c = 0; c < 2; ++c) {
    const int row = c * 32 + (tid >> 3);
    const int cb  = ((tid & 7) * 16) ^ ((row & 7) << 4);
    bSrc[c] = (const char*)Bp + ((size_t)(n0 + row) * K) * 4 + cb;
  }

  int aoff[4], boff[2];
#pragma unroll
  for (int t = 0; t < 4; ++t) {
    const int rA = wM + t * 16 + l15;
    aoff[t] = rA * 64 + ((lg * 16) ^ (((rA >> 1) & 3) << 4));
  }
#pragma unroll
  for (int t = 0; t < 2; ++t) {
    const int rB = wN + t * 16 + l15;
    boff[t] = rB * 128 + ((lg * 32) ^ ((rB & 7) << 4));
  }

  f32x4 acc[4][2];
#pragma unroll
  for (int i = 0; i < 4; ++i)
#pragma unroll
    for (int j = 0; j < 2; ++j) acc[i][j] = {0.f, 0.f, 0.f, 0.f};

  auto STG = [&](int kk, int bb) {
#pragma unroll
    for (int c = 0; c < 2; ++c) {
      GLDS16(aSrc[c] + (size_t)kk * 2, &As[bb][c * 4096 + wv * 1024]);
      GLDS16(bSrc[c] + (size_t)kk * 4, &Bs[bb][c * 4096 + wv * 1024]);
    }
  };

  STG(0, 0);
  __syncthreads();
  int cur = 0;
  for (int t = 0; t < K / 32; ++t) {
    if (t < K / 32 - 1) STG((t + 1) * 32, cur ^ 1);
    bf16x8 af[4], bfr[2];
#pragma unroll
    for (int x = 0; x < 4; ++x)
      af[x] = *(const bf16x8*)&As[cur][aoff[x]];
#pragma unroll
    for (int x = 0; x < 2; ++x) {
      f32x4 q0 = *(const f32x4*)&Bs[cur][boff[x]];
      f32x4 q1 = *(const f32x4*)&Bs[cur][boff[x] ^ 16];
      bfr[x] = cvt8(q0, q1);
    }
#pragma unroll
    for (int mt = 0; mt < 4; ++mt)
#pragma unroll
      for (int nt = 0; nt < 2; ++nt)
        acc[mt][nt] = __builtin_amdgcn_mfma_f32_16x16x32_bf16(af[mt], bfr[nt], acc[mt][nt], 0, 0, 0);
    __syncthreads();
    cur ^= 1;
  }

#pragma unroll
  for (int mt = 0; mt < 4; ++mt)
#pragma unroll
    for (int nt = 0; nt < 2; ++nt)
#pragma unroll
      for (int r = 0; r < 4; ++r) {
        const int row = m0 + wM + mt * 16 + lg * 4 + r;
        const int col = n0 + wN + nt * 16 + l15;
        __builtin_nontemporal_store(acc[mt][nt][r], Cp + (size_t)row * kH + col);
      }
}

// ---------------------------------------------------------------------------
// attn_rs: row sums only. 512 blocks x 4 waves (128 q-rows/block). K staged
// once per 128 rows (2 glds/thread/tile). Same summation order -> identical rs.
// ---------------------------------------------------------------------------
__global__ __launch_bounds__(256, 2) void attn_rs(
    const unsigned short* __restrict__ QP,
    const unsigned short* __restrict__ KP,
    float* __restrict__ rsout)          // [32][2048]
{
  __shared__ __align__(16) unsigned short Kb[2][4096];

  const int tid  = threadIdx.x;
  const int lane = tid & 63, wv = tid >> 6;
  const int l15  = lane & 15, lg = lane >> 4;
  const int f = blockIdx.x;
  const int x = f & 7, r = f >> 3;
  const int bn = (r >> 4) * 8 + x;      // 4 heads per XCD
  const int i0 = (r & 15) * 128;

  const char* Khb = (const char*)(KP + (size_t)bn * kHeadEls);
  const unsigned short* Qh = QP + (size_t)bn * kHeadEls;

  int kbase[2];
#pragma unroll
  for (int p = 0; p < 2; ++p) {
    const int row = p * 32 + (tid >> 3);
    kbase[p] = row * 128 + (((tid & 7) * 16) ^ ((row & 7) << 4));
  }
  auto STAGE = [&](int j0, int bb) {
#pragma unroll
    for (int p = 0; p < 2; ++p)
      GLDS16(Khb + (size_t)j0 * 128 + kbase[p], (char*)Kb[bb] + p * 4096 + tid * 16);
  };

  int koff[4][2];
#pragma unroll
  for (int ct = 0; ct < 4; ++ct) {
    const int rK = ct * 16 + l15;
#pragma unroll
    for (int h = 0; h < 2; ++h)
      koff[ct][h] = rK * 128 + ((h * 64 + lg * 16) ^ ((rK & 7) << 4));
  }

  bf16x8 qf[2][2];
#pragma unroll
  for (int m = 0; m < 2; ++m) {
    const int qr = i0 + wv * 32 + m * 16 + l15;
#pragma unroll
    for (int h = 0; h < 2; ++h)
      qf[m][h] = *(const bf16x8*)(Qh + (size_t)qr * kD + h * 32 + lg * 8);
  }
  const float cexp = 0.18033688011112042f;   // log2(e)/8

  float rs[2] = {0.f, 0.f};
  STAGE(0, 0);
  __syncthreads();
  int cur = 0;
  for (int t = 0; t < 32; ++t) {
    if (t < 31) STAGE((t + 1) * 64, cur ^ 1);
#pragma unroll
    for (int ct = 0; ct < 4; ++ct) {
      const bf16x8 kb0 = *(const bf16x8*)((const char*)Kb[cur] + koff[ct][0]);
      const bf16x8 kb1 = *(const bf16x8*)((const char*)Kb[cur] + koff[ct][1]);
#pragma unroll
      for (int m = 0; m < 2; ++m) {
        f32x4 s = {0.f, 0.f, 0.f, 0.f};
        s = __builtin_amdgcn_mfma_f32_16x16x32_bf16(kb0, qf[m][0], s, 0, 0, 0);
        s = __builtin_amdgcn_mfma_f32_16x16x32_bf16(kb1, qf[m][1], s, 0, 0, 0);
        const float w0 = fast_exp2(s[0] * cexp), w1 = fast_exp2(s[1] * cexp);
        const float w2 = fast_exp2(s[2] * cexp), w3 = fast_exp2(s[3] * cexp);
        rs[m] += (w0 + w1) + (w2 + w3);
      }
    }
    __syncthreads();
    cur ^= 1;
  }
#pragma unroll
  for (int m = 0; m < 2; ++m) {
    rs[m] += __shfl_xor(rs[m], 16, 64);
    rs[m] += __shfl_xor(rs[m], 32, 64);
  }
  if (lg == 0) {
#pragma unroll
    for (int m = 0; m < 2; ++m)
      rsout[(size_t)bn * kS + i0 + wv * 32 + m * 16 + l15] = rs[m];
  }
}

// ---------------------------------------------------------------------------
// attn_main: QK^T -> normalized w -> Ws (bf16) -> PV + full-line AW stores
// via Ws readback (round-9 proven). Now 512 blocks x 4 waves (128 rows):
// halved staging, 12 waves/CU. Per tile: 4 glds + 8 AW stores; vmcnt(8)
// retires glds, keeps stores flying across the raw s_barrier.
// ---------------------------------------------------------------------------
__global__ __launch_bounds__(256, 3) void attn_main(
    const unsigned short* __restrict__ QP,
    const unsigned short* __restrict__ KP,
    const unsigned short* __restrict__ VPT,
    const float* __restrict__ rsb,      // [32][2048]
    float* __restrict__ AW,             // [32][2048][2048] fp32
    unsigned short* __restrict__ XB)    // [4096][1024] bf16
{
  __shared__ __align__(16) unsigned short Kb[2][4096];   // [64 j][64 d] swz
  __shared__ __align__(16) unsigned short Vb[2][4096];   // [64 d][64 j] swz
  __shared__ __align__(16) unsigned short Ws[8192];      // [128 q][64 j] swz

  const int tid  = threadIdx.x;
  const int lane = tid & 63, wv = tid >> 6;
  const int l15  = lane & 15, lg = lane >> 4;
  const int f = blockIdx.x;
  const int x = f & 7, r = f >> 3;
  const int bn = (r >> 4) * 8 + x;      // 4 heads per XCD
  const int i0 = (r & 15) * 128;
  const int b = bn >> 4, n = bn & 15;

  const char* Khb = (const char*)(KP + (size_t)bn * kHeadEls);
  const char* Vhb = (const char*)(VPT + (size_t)bn * kHeadEls);
  const unsigned short* Qh = QP + (size_t)bn * kHeadEls;

  int kbase[2], vbase[2];
#pragma unroll
  for (int p = 0; p < 2; ++p) {
    const int row = p * 32 + (tid >> 3);
    const int sw  = ((tid & 7) * 16) ^ ((row & 7) << 4);
    kbase[p] = row * 128 + sw;          // K: row = j
    vbase[p] = row * 4096 + sw;         // V: row = d (VPT row stride 4096 B)
  }
  auto STAGE_KV = [&](int j0, int bb) {
#pragma unroll
    for (int p = 0; p < 2; ++p) {
      GLDS16(Khb + (size_t)j0 * 128 + kbase[p], (char*)Kb[bb] + p * 4096 + tid * 16);
      GLDS16(Vhb + (size_t)j0 * 2 + vbase[p],   (char*)Vb[bb] + p * 4096 + tid * 16);
    }
  };

  int koff[4][2], voff[2][4], wswr[2][4], wsrd[2][2];
#pragma unroll
  for (int ct = 0; ct < 4; ++ct) {
    const int rK = ct * 16 + l15;
#pragma unroll
    for (int h = 0; h < 2; ++h)
      koff[ct][h] = rK * 128 + ((h * 64 + lg * 16) ^ ((rK & 7) << 4));
  }
#pragma unroll
  for (int jc = 0; jc < 2; ++jc)
#pragma unroll
    for (int dt = 0; dt < 4; ++dt) {
      const int d = dt * 16 + l15;
      voff[jc][dt] = d * 128 + ((jc * 64 + lg * 16) ^ ((d & 7) << 4));
    }
#pragma unroll
  for (int m = 0; m < 2; ++m) {
    const int rw = wv * 32 + m * 16 + l15;
#pragma unroll
    for (int ct = 0; ct < 4; ++ct)
      wswr[m][ct] = rw * 128 + ((ct * 32 + lg * 8) ^ ((rw & 7) << 4));
#pragma unroll
    for (int jc = 0; jc < 2; ++jc)
      wsrd[m][jc] = rw * 128 + ((jc * 64 + lg * 16) ^ ((rw & 7) << 4));
  }

  // AW full-line store descriptors: instr u covers rows wv*32+u*4+lg,
  // lane l15 reads 4 consecutive j -> 4 rows x 256 B (full 128B lines).
  int awrd[8];
  float* awp[8];
#pragma unroll
  for (int u = 0; u < 8; ++u) {
    const int rw = wv * 32 + u * 4 + lg;
    awrd[u] = rw * 128 + ((l15 * 8) ^ ((rw & 7) << 4));
    awp[u]  = AW + ((size_t)bn * kS + i0 + rw) * kS + l15 * 4;
  }

  bf16x8 qf[2][2];
  float inv[2];
#pragma unroll
  for (int m = 0; m < 2; ++m) {
    const int qr = i0 + wv * 32 + m * 16 + l15;
#pragma unroll
    for (int h = 0; h < 2; ++h)
      qf[m][h] = *(const bf16x8*)(Qh + (size_t)qr * kD + h * 32 + lg * 8);
    inv[m] = 1.0f / rsb[(size_t)bn * kS + qr];
  }
  const float cexp = 0.18033688011112042f;   // log2(e)/8

  f32x4 pv[2][4];
#pragma unroll
  for (int m = 0; m < 2; ++m)
#pragma unroll
    for (int dt = 0; dt < 4; ++dt) pv[m][dt] = {0.f, 0.f, 0.f, 0.f};

  STAGE_KV(0, 0);
  asm volatile("s_waitcnt vmcnt(0) lgkmcnt(0)" ::: "memory");
  __builtin_amdgcn_sched_barrier(0);
  __builtin_amdgcn_s_barrier();

  int cur = 0;
  for (int t = 0; t < 32; ++t) {
    if (t < 31) STAGE_KV((t + 1) * 64, cur ^ 1);   // 4 glds, oldest in queue
    __builtin_amdgcn_sched_barrier(0);             // pin glds before AW stores
    // QK^T (swapped) -> normalized w -> Ws write (bf16)
#pragma unroll
    for (int ct = 0; ct < 4; ++ct) {
      const bf16x8 kb0 = *(const bf16x8*)((const char*)Kb[cur] + koff[ct][0]);
      const bf16x8 kb1 = *(const bf16x8*)((const char*)Kb[cur] + koff[ct][1]);
#pragma unroll
      for (int m = 0; m < 2; ++m) {
        f32x4 s = {0.f, 0.f, 0.f, 0.f};
        s = __builtin_amdgcn_mfma_f32_16x16x32_bf16(kb0, qf[m][0], s, 0, 0, 0);
        s = __builtin_amdgcn_mfma_f32_16x16x32_bf16(kb1, qf[m][1], s, 0, 0, 0);
        f32x4 w;
#pragma unroll
        for (int r2 = 0; r2 < 4; ++r2) w[r2] = fast_exp2(s[r2] * cexp) * inv[m];
        u32x2 pk; pk[0] = cvt_pk(w[0], w[1]); pk[1] = cvt_pk(w[2], w[3]);
        *(u32x2*)((char*)Ws + wswr[m][ct]) = pk;   // wave-private rows
      }
    }
    // PV (same-wave Ws dep)
#pragma unroll
    for (int jc = 0; jc < 2; ++jc) {
      const bf16x8 pa0 = *(const bf16x8*)((const char*)Ws + wsrd[0][jc]);
      const bf16x8 pa1 = *(const bf16x8*)((const char*)Ws + wsrd[1][jc]);
#pragma unroll
      for (int dt = 0; dt < 4; ++dt) {
        const bf16x8 vf = *(const bf16x8*)((const char*)Vb[cur] + voff[jc][dt]);
        pv[0][dt] = __builtin_amdgcn_mfma_f32_16x16x32_bf16(pa0, vf, pv[0][dt], 0, 0, 0);
        pv[1][dt] = __builtin_amdgcn_mfma_f32_16x16x32_bf16(pa1, vf, pv[1][dt], 0, 0, 0);
      }
    }
    // AW stores: Ws readback row-contiguous -> full-line store instrs
#pragma unroll
    for (int u = 0; u < 8; ++u) {
      const u32x2 pk = *(const u32x2*)((const char*)Ws + awrd[u]);
      f32x4 w;
      w[0] = bf2f(pk[0] & 0xFFFFu);
      w[1] = bf2f(pk[0] >> 16);
      w[2] = bf2f(pk[1] & 0xFFFFu);
      w[3] = bf2f(pk[1] >> 16);
      __builtin_nontemporal_store(w, (f32x4*)(awp[u] + t * 64));
    }
    if (t < 31) {
      // retire this wave's 4 glds (older than the 8 stores); stores fly
      asm volatile("s_waitcnt vmcnt(8) lgkmcnt(0)" ::: "memory");
      __builtin_amdgcn_sched_barrier(0);
      __builtin_amdgcn_s_barrier();
    }
    cur ^= 1;
  }

  // XB epilogue: PV already normalized
#pragma unroll
  for (int m = 0; m < 2; ++m)
#pragma unroll
    for (int dt = 0; dt < 4; ++dt)
#pragma unroll
      for (int r2 = 0; r2 < 4; ++r2) {
        const int row = b * kS + i0 + wv * 32 + m * 16 + lg * 4 + r2;  // (b,i)
        const int col = n * 64 + dt * 16 + l15;                        // (n d)
        XB[(size_t)row * kH + col] = f2bf(pv[m][dt][r2]);
      }
}

// ---------------------------------------------------------------------------
extern "C" void kernel_launch(void* const* d_in, const int* in_sizes, int n_in,
                              void* d_out, int out_size, void* d_ws, size_t ws_size,
                              hipStream_t stream) {
  const float* q  = (const float*)d_in[0];
  const float* k  = (const float*)d_in[1];
  const float* v  = (const float*)d_in[2];
  const float* Wq = (const float*)d_in[3];
  const float* Wk = (const float*)d_in[4];
  const float* Wv = (const float*)d_in[5];
  const float* Wo = (const float*)d_in[6];

  float* out = (float*)d_out;
  float* aw  = out + (size_t)kBS * kH;
  float* rsb = out;   // row sums stashed in out; final GEMM overwrites

  unsigned short* QP  = (unsigned short*)d_ws;         // 8 MB
  unsigned short* KP  = QP  + (size_t)kBS * kH;        // 8 MB
  unsigned short* VPT = KP  + (size_t)kBS * kH;        // 8 MB
  unsigned short* XB  = VPT + (size_t)kBS * kH;        // 8 MB (total 32 MB)

  // bf16 W copies in AW region: consumed by proj before attn writes AW
  unsigned short* stash = (unsigned short*)aw;
  unsigned short* Wqb = stash;
  unsigned short* Wkb = stash + (size_t)kH * kH;
  unsigned short* Wvb = stash + (size_t)2 * kH * kH;

  cvt_w<<<dim3(512, 3), 256, 0, stream>>>(Wq, Wk, Wv, Wqb, Wkb, Wvb);
  gemm_p<<<dim3(8, 32, 3), 256, 0, stream>>>(q, k, v, Wqb, Wkb, Wvb, QP, KP, VPT);
  attn_rs<<<dim3(512), 256, 0, stream>>>(QP, KP, rsb);
  attn_main<<<dim3(512), 256, 0, stream>>>(QP, KP, VPT, rsb, aw, XB);
  gemm_f<<<dim3(16, 32), 256, 0, stream>>>(XB, Wo, out);
}

// Round 11
// 247.513 us; speedup vs baseline: 1.3530x; 1.0550x over previous
//
#include <hip/hip_runtime.h>
#include <hip/hip_bf16.h>

#define DEVI __device__ __forceinline__

constexpr int kS  = 2048;
constexpr int kH  = 1024;
constexpr int kD  = 64;
constexpr int kBS = 4096;            // B*S
constexpr int kHeadEls = kS * kD;    // elements per (b,head) chunk

typedef __attribute__((ext_vector_type(4))) float f32x4;
typedef __attribute__((ext_vector_type(8))) __bf16 bf16x8;
typedef __attribute__((ext_vector_type(8))) unsigned short u16x8;
typedef __attribute__((ext_vector_type(2))) unsigned int u32x2;

DEVI unsigned short f2bf(float f) {            // RNE fp32 -> bf16
  unsigned int u = __builtin_bit_cast(unsigned int, f);
  u = u + 0x7FFFu + ((u >> 16) & 1u);
  return (unsigned short)(u >> 16);
}
DEVI float fast_exp2(float x) { float r; asm("v_exp_f32 %0, %1" : "=v"(r) : "v"(x)); return r; }
DEVI unsigned int cvt_pk(float lo, float hi) {
  unsigned int r; asm("v_cvt_pk_bf16_f32 %0, %1, %2" : "=v"(r) : "v"(lo), "v"(hi)); return r;
}
DEVI bf16x8 cvt8(const f32x4 a, const f32x4 b) {
  union { unsigned int u[4]; bf16x8 v; } r;
  r.u[0] = cvt_pk(a[0], a[1]); r.u[1] = cvt_pk(a[2], a[3]);
  r.u[2] = cvt_pk(b[0], b[1]); r.u[3] = cvt_pk(b[2], b[3]);
  return r.v;
}
DEVI float bf2f(unsigned int lo16) {           // bf16 (low 16 bits) -> f32
  return __builtin_bit_cast(float, lo16 << 16);
}

#define GLDS16(g, l) __builtin_amdgcn_global_load_lds( \
    (const __attribute__((address_space(1))) void*)(g), \
    (__attribute__((address_space(3))) void*)(l), 16, 0, 0)

// ---------------------------------------------------------------------------
// fp32 -> bf16 pre-convert: q,k,v (4M els each) and Wq,Wk,Wv (1M each) into
// the AW-region stash (AW is only written later by attn_main).
// ---------------------------------------------------------------------------
__global__ __launch_bounds__(256) void cvt_all(
    const float* __restrict__ q, const float* __restrict__ k, const float* __restrict__ v,
    const float* __restrict__ Wq, const float* __restrict__ Wk, const float* __restrict__ Wv,
    unsigned short* __restrict__ stash)
{
  const int z = blockIdx.y, x = blockIdx.x;
  const float* s;
  unsigned short* d;
  size_t i;
  if (x < 2048) {
    s = z == 0 ? q : z == 1 ? k : v;
    d = stash + (size_t)z * 4194304;
    i = ((size_t)x * 256 + threadIdx.x) * 8;
  } else {
    s = z == 0 ? Wq : z == 1 ? Wk : Wv;
    d = stash + (size_t)12582912 + (size_t)z * 1048576;
    i = ((size_t)(x - 2048) * 256 + threadIdx.x) * 8;
  }
  f32x4 a = *(const f32x4*)(s + i);
  f32x4 b = *(const f32x4*)(s + i + 4);
  union { unsigned int u[4]; u16x8 v; } r;
  r.u[0] = cvt_pk(a[0], a[1]); r.u[1] = cvt_pk(a[2], a[3]);
  r.u[2] = cvt_pk(b[0], b[1]); r.u[3] = cvt_pk(b[2], b[3]);
  *(u16x8*)(d + i) = r.v;
}

// ---------------------------------------------------------------------------
// Projection GEMM, all-bf16 (R5-proven): C = A @ B^T, M=4096 N=1024 K=1024.
// 2-phase dbuf glds staging, 2+2 glds/thread/tile, no in-loop conversion.
// z==2 writes the transposed per-head VPT layout. LDS 32 KB -> 3 blocks/CU.
// ---------------------------------------------------------------------------
__global__ __launch_bounds__(256, 3) void gemm_p(
    const unsigned short* __restrict__ Aq, const unsigned short* __restrict__ Ak,
    const unsigned short* __restrict__ Av,
    const unsigned short* __restrict__ Bq, const unsigned short* __restrict__ Bk,
    const unsigned short* __restrict__ Bv,
    unsigned short* __restrict__ Cq, unsigned short* __restrict__ Ck,
    unsigned short* __restrict__ Cv)
{
  constexpr int K = kH;
  __shared__ __align__(16) unsigned char As[2][8192];
  __shared__ __align__(16) unsigned char Bs[2][8192];

  const int z = blockIdx.z;
  const unsigned short* Ap = z == 0 ? Aq : z == 1 ? Ak : Av;
  const unsigned short* Bp = z == 0 ? Bq : z == 1 ? Bk : Bv;
  unsigned short*       Cp = z == 0 ? Cq : z == 1 ? Ck : Cv;

  const int tid  = threadIdx.x;
  const int lane = tid & 63, wv = tid >> 6;
  const int l15  = lane & 15, lg = lane >> 4;
  const int m0 = blockIdx.y * 128, n0 = blockIdx.x * 128;
  const int wM = (wv & 1) * 64, wN = (wv >> 1) * 64;

  // pre-swizzled sources (bf16: byte ^= ((row>>1)&3)<<4)
  const char* aSrc[2];
  const char* bSrc[2];
#pragma unroll
  for (int c = 0; c < 2; ++c) {
    const int row = c * 64 + (tid >> 2);
    const int cb  = ((tid & 3) * 16) ^ (((row >> 1) & 3) << 4);
    aSrc[c] = (const char*)Ap + ((size_t)(m0 + row) * K) * 2 + cb;
    bSrc[c] = (const char*)Bp + ((size_t)(n0 + row) * K) * 2 + cb;
  }

  int aoff[4], boff[4];
#pragma unroll
  for (int t = 0; t < 4; ++t) {
    const int rA = wM + t * 16 + l15;
    aoff[t] = rA * 64 + ((lg * 16) ^ (((rA >> 1) & 3) << 4));
    const int rB = wN + t * 16 + l15;
    boff[t] = rB * 64 + ((lg * 16) ^ (((rB >> 1) & 3) << 4));
  }

  f32x4 acc[4][4];
#pragma unroll
  for (int i = 0; i < 4; ++i)
#pragma unroll
    for (int j = 0; j < 4; ++j) acc[i][j] = {0.f, 0.f, 0.f, 0.f};

  auto STG = [&](int kk, int bb) {
#pragma unroll
    for (int c = 0; c < 2; ++c) {
      GLDS16(aSrc[c] + (size_t)kk * 2, &As[bb][c * 4096 + wv * 1024]);
      GLDS16(bSrc[c] + (size_t)kk * 2, &Bs[bb][c * 4096 + wv * 1024]);
    }
  };

  STG(0, 0);
  __syncthreads();
  int cur = 0;
  for (int t = 0; t < K / 32; ++t) {
    if (t < K / 32 - 1) STG((t + 1) * 32, cur ^ 1);
    bf16x8 af[4], bfr[4];
#pragma unroll
    for (int x = 0; x < 4; ++x) {
      af[x]  = *(const bf16x8*)&As[cur][aoff[x]];
      bfr[x] = *(const bf16x8*)&Bs[cur][boff[x]];
    }
#pragma unroll
    for (int mt = 0; mt < 4; ++mt)
#pragma unroll
      for (int nt = 0; nt < 4; ++nt)
        acc[mt][nt] = __builtin_amdgcn_mfma_f32_16x16x32_bf16(af[mt], bfr[nt], acc[mt][nt], 0, 0, 0);
    __syncthreads();   // drains next-tile staging (in flight during compute)
    cur ^= 1;
  }

  const bool vmode = (z == 2);
#pragma unroll
  for (int mt = 0; mt < 4; ++mt)
#pragma unroll
    for (int nt = 0; nt < 4; ++nt)
#pragma unroll
      for (int r = 0; r < 4; ++r) {
        const int row = m0 + wM + mt * 16 + lg * 4 + r;
        const int col = n0 + wN + nt * 16 + l15;
        const unsigned short hv = f2bf(acc[mt][nt][r]);
        if (!vmode) {
          Cp[(size_t)row * kH + col] = hv;
        } else {
          const int bn = row >> 7;                       // VPT[bn][d][j]
          const int j  = ((row & 127) << 4) | (col >> 6);
          const int d  = col & 63;
          Cp[(size_t)bn * kHeadEls + (size_t)d * kS + j] = hv;
        }
      }
}

// ---------------------------------------------------------------------------
// Final GEMM: out = XB @ Wo^T, tile 128x64 -> grid (16,32)=512 blocks (2/CU).
// A bf16 (XB), B fp32 (Wo, cvt inline), C fp32 nontemporal. LDS 32 KB.
// (R10-proven, unchanged.)
// ---------------------------------------------------------------------------
__global__ __launch_bounds__(256, 3) void gemm_f(
    const unsigned short* __restrict__ Ap, const float* __restrict__ Bp,
    float* __restrict__ Cp)
{
  constexpr int K = kH;
  __shared__ __align__(16) unsigned char As[2][8192];
  __shared__ __align__(16) unsigned char Bs[2][8192];

  const int tid  = threadIdx.x;
  const int lane = tid & 63, wv = tid >> 6;
  const int l15  = lane & 15, lg = lane >> 4;
  const int m0 = blockIdx.y * 128, n0 = blockIdx.x * 64;
  const int wM = (wv & 1) * 64, wN = (wv >> 1) * 32;

  const char* aSrc[2];
#pragma unroll
  for (int c = 0; c < 2; ++c) {
    const int row = c * 64 + (tid >> 2);
    const int cb  = ((tid & 3) * 16) ^ (((row >> 1) & 3) << 4);
    aSrc[c] = (const char*)Ap + ((size_t)(m0 + row) * K) * 2 + cb;
  }
  const char* bSrc[2];
#pragma unroll
  for (int c = 0; c < 2; ++c) {
    const int row = c * 32 + (tid >> 3);
    const int cb  = ((tid & 7) * 16) ^ ((row & 7) << 4);
    bSrc[c] = (const char*)Bp + ((size_t)(n0 + row) * K) * 4 + cb;
  }

  int aoff[4], boff[2];
#pragma unroll
  for (int t = 0; t < 4; ++t) {
    const int rA = wM + t * 16 + l15;
    aoff[t] = rA * 64 + ((lg * 16) ^ (((rA >> 1) & 3) << 4));
  }
#pragma unroll
  for (int t = 0; t < 2; ++t) {
    const int rB = wN + t * 16 + l15;
    boff[t] = rB * 128 + ((lg * 32) ^ ((rB & 7) << 4));
  }

  f32x4 acc[4][2];
#pragma unroll
  for (int i = 0; i < 4; ++i)
#pragma unroll
    for (int j = 0; j < 2; ++j) acc[i][j] = {0.f, 0.f, 0.f, 0.f};

  auto STG = [&](int kk, int bb) {
#pragma unroll
    for (int c = 0; c < 2; ++c) {
      GLDS16(aSrc[c] + (size_t)kk * 2, &As[bb][c * 4096 + wv * 1024]);
      GLDS16(bSrc[c] + (size_t)kk * 4, &Bs[bb][c * 4096 + wv * 1024]);
    }
  };

  STG(0, 0);
  __syncthreads();
  int cur = 0;
  for (int t = 0; t < K / 32; ++t) {
    if (t < K / 32 - 1) STG((t + 1) * 32, cur ^ 1);
    bf16x8 af[4], bfr[2];
#pragma unroll
    for (int x = 0; x < 4; ++x)
      af[x] = *(const bf16x8*)&As[cur][aoff[x]];
#pragma unroll
    for (int x = 0; x < 2; ++x) {
      f32x4 q0 = *(const f32x4*)&Bs[cur][boff[x]];
      f32x4 q1 = *(const f32x4*)&Bs[cur][boff[x] ^ 16];
      bfr[x] = cvt8(q0, q1);
    }
#pragma unroll
    for (int mt = 0; mt < 4; ++mt)
#pragma unroll
      for (int nt = 0; nt < 2; ++nt)
        acc[mt][nt] = __builtin_amdgcn_mfma_f32_16x16x32_bf16(af[mt], bfr[nt], acc[mt][nt], 0, 0, 0);
    __syncthreads();
    cur ^= 1;
  }

#pragma unroll
  for (int mt = 0; mt < 4; ++mt)
#pragma unroll
    for (int nt = 0; nt < 2; ++nt)
#pragma unroll
      for (int r = 0; r < 4; ++r) {
        const int row = m0 + wM + mt * 16 + lg * 4 + r;
        const int col = n0 + wN + nt * 16 + l15;
        __builtin_nontemporal_store(acc[mt][nt][r], Cp + (size_t)row * kH + col);
      }
}

// ---------------------------------------------------------------------------
// attn_rs: row sums only (R10-proven, unchanged). 512 blocks x 4 waves.
// ---------------------------------------------------------------------------
__global__ __launch_bounds__(256, 2) void attn_rs(
    const unsigned short* __restrict__ QP,
    const unsigned short* __restrict__ KP,
    float* __restrict__ rsout)          // [32][2048]
{
  __shared__ __align__(16) unsigned short Kb[2][4096];

  const int tid  = threadIdx.x;
  const int lane = tid & 63, wv = tid >> 6;
  const int l15  = lane & 15, lg = lane >> 4;
  const int f = blockIdx.x;
  const int x = f & 7, r = f >> 3;
  const int bn = (r >> 4) * 8 + x;      // 4 heads per XCD
  const int i0 = (r & 15) * 128;

  const char* Khb = (const char*)(KP + (size_t)bn * kHeadEls);
  const unsigned short* Qh = QP + (size_t)bn * kHeadEls;

  int kbase[2];
#pragma unroll
  for (int p = 0; p < 2; ++p) {
    const int row = p * 32 + (tid >> 3);
    kbase[p] = row * 128 + (((tid & 7) * 16) ^ ((row & 7) << 4));
  }
  auto STAGE = [&](int j0, int bb) {
#pragma unroll
    for (int p = 0; p < 2; ++p)
      GLDS16(Khb + (size_t)j0 * 128 + kbase[p], (char*)Kb[bb] + p * 4096 + tid * 16);
  };

  int koff[4][2];
#pragma unroll
  for (int ct = 0; ct < 4; ++ct) {
    const int rK = ct * 16 + l15;
#pragma unroll
    for (int h = 0; h < 2; ++h)
      koff[ct][h] = rK * 128 + ((h * 64 + lg * 16) ^ ((rK & 7) << 4));
  }

  bf16x8 qf[2][2];
#pragma unroll
  for (int m = 0; m < 2; ++m) {
    const int qr = i0 + wv * 32 + m * 16 + l15;
#pragma unroll
    for (int h = 0; h < 2; ++h)
      qf[m][h] = *(const bf16x8*)(Qh + (size_t)qr * kD + h * 32 + lg * 8);
  }
  const float cexp = 0.18033688011112042f;   // log2(e)/8

  float rs[2] = {0.f, 0.f};
  STAGE(0, 0);
  __syncthreads();
  int cur = 0;
  for (int t = 0; t < 32; ++t) {
    if (t < 31) STAGE((t + 1) * 64, cur ^ 1);
#pragma unroll
    for (int ct = 0; ct < 4; ++ct) {
      const bf16x8 kb0 = *(const bf16x8*)((const char*)Kb[cur] + koff[ct][0]);
      const bf16x8 kb1 = *(const bf16x8*)((const char*)Kb[cur] + koff[ct][1]);
#pragma unroll
      for (int m = 0; m < 2; ++m) {
        f32x4 s = {0.f, 0.f, 0.f, 0.f};
        s = __builtin_amdgcn_mfma_f32_16x16x32_bf16(kb0, qf[m][0], s, 0, 0, 0);
        s = __builtin_amdgcn_mfma_f32_16x16x32_bf16(kb1, qf[m][1], s, 0, 0, 0);
        const float w0 = fast_exp2(s[0] * cexp), w1 = fast_exp2(s[1] * cexp);
        const float w2 = fast_exp2(s[2] * cexp), w3 = fast_exp2(s[3] * cexp);
        rs[m] += (w0 + w1) + (w2 + w3);
      }
    }
    __syncthreads();
    cur ^= 1;
  }
#pragma unroll
  for (int m = 0; m < 2; ++m) {
    rs[m] += __shfl_xor(rs[m], 16, 64);
    rs[m] += __shfl_xor(rs[m], 32, 64);
  }
  if (lg == 0) {
#pragma unroll
    for (int m = 0; m < 2; ++m)
      rsout[(size_t)bn * kS + i0 + wv * 32 + m * 16 + l15] = rs[m];
  }
}

// ---------------------------------------------------------------------------
// attn_main (R10-proven, unchanged): QK^T -> normalized w -> Ws (bf16) -> PV,
// AW via row-contiguous Ws readback -> full-line NT stores; counted vmcnt(8)
// + raw s_barrier keeps stores flying.
// ---------------------------------------------------------------------------
__global__ __launch_bounds__(256, 3) void attn_main(
    const unsigned short* __restrict__ QP,
    const unsigned short* __restrict__ KP,
    const unsigned short* __restrict__ VPT,
    const float* __restrict__ rsb,      // [32][2048]
    float* __restrict__ AW,             // [32][2048][2048] fp32
    unsigned short* __restrict__ XB)    // [4096][1024] bf16
{
  __shared__ __align__(16) unsigned short Kb[2][4096];   // [64 j][64 d] swz
  __shared__ __align__(16) unsigned short Vb[2][4096];   // [64 d][64 j] swz
  __shared__ __align__(16) unsigned short Ws[8192];      // [128 q][64 j] swz

  const int tid  = threadIdx.x;
  const int lane = tid & 63, wv = tid >> 6;
  const int l15  = lane & 15, lg = lane >> 4;
  const int f = blockIdx.x;
  const int x = f & 7, r = f >> 3;
  const int bn = (r >> 4) * 8 + x;      // 4 heads per XCD
  const int i0 = (r & 15) * 128;
  const int b = bn >> 4, n = bn & 15;

  const char* Khb = (const char*)(KP + (size_t)bn * kHeadEls);
  const char* Vhb = (const char*)(VPT + (size_t)bn * kHeadEls);
  const unsigned short* Qh = QP + (size_t)bn * kHeadEls;

  int kbase[2], vbase[2];
#pragma unroll
  for (int p = 0; p < 2; ++p) {
    const int row = p * 32 + (tid >> 3);
    const int sw  = ((tid & 7) * 16) ^ ((row & 7) << 4);
    kbase[p] = row * 128 + sw;          // K: row = j
    vbase[p] = row * 4096 + sw;         // V: row = d (VPT row stride 4096 B)
  }
  auto STAGE_KV = [&](int j0, int bb) {
#pragma unroll
    for (int p = 0; p < 2; ++p) {
      GLDS16(Khb + (size_t)j0 * 128 + kbase[p], (char*)Kb[bb] + p * 4096 + tid * 16);
      GLDS16(Vhb + (size_t)j0 * 2 + vbase[p],   (char*)Vb[bb] + p * 4096 + tid * 16);
    }
  };

  int koff[4][2], voff[2][4], wswr[2][4], wsrd[2][2];
#pragma unroll
  for (int ct = 0; ct < 4; ++ct) {
    const int rK = ct * 16 + l15;
#pragma unroll
    for (int h = 0; h < 2; ++h)
      koff[ct][h] = rK * 128 + ((h * 64 + lg * 16) ^ ((rK & 7) << 4));
  }
#pragma unroll
  for (int jc = 0; jc < 2; ++jc)
#pragma unroll
    for (int dt = 0; dt < 4; ++dt) {
      const int d = dt * 16 + l15;
      voff[jc][dt] = d * 128 + ((jc * 64 + lg * 16) ^ ((d & 7) << 4));
    }
#pragma unroll
  for (int m = 0; m < 2; ++m) {
    const int rw = wv * 32 + m * 16 + l15;
#pragma unroll
    for (int ct = 0; ct < 4; ++ct)
      wswr[m][ct] = rw * 128 + ((ct * 32 + lg * 8) ^ ((rw & 7) << 4));
#pragma unroll
    for (int jc = 0; jc < 2; ++jc)
      wsrd[m][jc] = rw * 128 + ((jc * 64 + lg * 16) ^ ((rw & 7) << 4));
  }

  int awrd[8];
  float* awp[8];
#pragma unroll
  for (int u = 0; u < 8; ++u) {
    const int rw = wv * 32 + u * 4 + lg;
    awrd[u] = rw * 128 + ((l15 * 8) ^ ((rw & 7) << 4));
    awp[u]  = AW + ((size_t)bn * kS + i0 + rw) * kS + l15 * 4;
  }

  bf16x8 qf[2][2];
  float inv[2];
#pragma unroll
  for (int m = 0; m < 2; ++m) {
    const int qr = i0 + wv * 32 + m * 16 + l15;
#pragma unroll
    for (int h = 0; h < 2; ++h)
      qf[m][h] = *(const bf16x8*)(Qh + (size_t)qr * kD + h * 32 + lg * 8);
    inv[m] = 1.0f / rsb[(size_t)bn * kS + qr];
  }
  const float cexp = 0.18033688011112042f;   // log2(e)/8

  f32x4 pv[2][4];
#pragma unroll
  for (int m = 0; m < 2; ++m)
#pragma unroll
    for (int dt = 0; dt < 4; ++dt) pv[m][dt] = {0.f, 0.f, 0.f, 0.f};

  STAGE_KV(0, 0);
  asm volatile("s_waitcnt vmcnt(0) lgkmcnt(0)" ::: "memory");
  __builtin_amdgcn_sched_barrier(0);
  __builtin_amdgcn_s_barrier();

  int cur = 0;
  for (int t = 0; t < 32; ++t) {
    if (t < 31) STAGE_KV((t + 1) * 64, cur ^ 1);   // 4 glds, oldest in queue
    __builtin_amdgcn_sched_barrier(0);             // pin glds before AW stores
#pragma unroll
    for (int ct = 0; ct < 4; ++ct) {
      const bf16x8 kb0 = *(const bf16x8*)((const char*)Kb[cur] + koff[ct][0]);
      const bf16x8 kb1 = *(const bf16x8*)((const char*)Kb[cur] + koff[ct][1]);
#pragma unroll
      for (int m = 0; m < 2; ++m) {
        f32x4 s = {0.f, 0.f, 0.f, 0.f};
        s = __builtin_amdgcn_mfma_f32_16x16x32_bf16(kb0, qf[m][0], s, 0, 0, 0);
        s = __builtin_amdgcn_mfma_f32_16x16x32_bf16(kb1, qf[m][1], s, 0, 0, 0);
        f32x4 w;
#pragma unroll
        for (int r2 = 0; r2 < 4; ++r2) w[r2] = fast_exp2(s[r2] * cexp) * inv[m];
        u32x2 pk; pk[0] = cvt_pk(w[0], w[1]); pk[1] = cvt_pk(w[2], w[3]);
        *(u32x2*)((char*)Ws + wswr[m][ct]) = pk;   // wave-private rows
      }
    }
#pragma unroll
    for (int jc = 0; jc < 2; ++jc) {
      const bf16x8 pa0 = *(const bf16x8*)((const char*)Ws + wsrd[0][jc]);
      const bf16x8 pa1 = *(const bf16x8*)((const char*)Ws + wsrd[1][jc]);
#pragma unroll
      for (int dt = 0; dt < 4; ++dt) {
        const bf16x8 vf = *(const bf16x8*)((const char*)Vb[cur] + voff[jc][dt]);
        pv[0][dt] = __builtin_amdgcn_mfma_f32_16x16x32_bf16(pa0, vf, pv[0][dt], 0, 0, 0);
        pv[1][dt] = __builtin_amdgcn_mfma_f32_16x16x32_bf16(pa1, vf, pv[1][dt], 0, 0, 0);
      }
    }
#pragma unroll
    for (int u = 0; u < 8; ++u) {
      const u32x2 pk = *(const u32x2*)((const char*)Ws + awrd[u]);
      f32x4 w;
      w[0] = bf2f(pk[0] & 0xFFFFu);
      w[1] = bf2f(pk[0] >> 16);
      w[2] = bf2f(pk[1] & 0xFFFFu);
      w[3] = bf2f(pk[1] >> 16);
      __builtin_nontemporal_store(w, (f32x4*)(awp[u] + t * 64));
    }
    if (t < 31) {
      asm volatile("s_waitcnt vmcnt(8) lgkmcnt(0)" ::: "memory");
      __builtin_amdgcn_sched_barrier(0);
      __builtin_amdgcn_s_barrier();
    }
    cur ^= 1;
  }

#pragma unroll
  for (int m = 0; m < 2; ++m)
#pragma unroll
    for (int dt = 0; dt < 4; ++dt)
#pragma unroll
      for (int r2 = 0; r2 < 4; ++r2) {
        const int row = b * kS + i0 + wv * 32 + m * 16 + lg * 4 + r2;  // (b,i)
        const int col = n * 64 + dt * 16 + l15;                        // (n d)
        XB[(size_t)row * kH + col] = f2bf(pv[m][dt][r2]);
      }
}

// ---------------------------------------------------------------------------
extern "C" void kernel_launch(void* const* d_in, const int* in_sizes, int n_in,
                              void* d_out, int out_size, void* d_ws, size_t ws_size,
                              hipStream_t stream) {
  const float* q  = (const float*)d_in[0];
  const float* k  = (const float*)d_in[1];
  const float* v  = (const float*)d_in[2];
  const float* Wq = (const float*)d_in[3];
  const float* Wk = (const float*)d_in[4];
  const float* Wv = (const float*)d_in[5];
  const float* Wo = (const float*)d_in[6];

  float* out = (float*)d_out;
  float* aw  = out + (size_t)kBS * kH;
  float* rsb = out;   // row sums stashed in out; gemm_f overwrites

  unsigned short* QP  = (unsigned short*)d_ws;         // 8 MB
  unsigned short* KP  = QP  + (size_t)kBS * kH;        // 8 MB
  unsigned short* VPT = KP  + (size_t)kBS * kH;        // 8 MB
  unsigned short* XB  = VPT + (size_t)kBS * kH;        // 8 MB (total 32 MB)

  // bf16 stash in AW region: consumed by gemm_p before attn_main writes AW
  unsigned short* stash = (unsigned short*)aw;
  unsigned short* QB  = stash;
  unsigned short* KB  = stash + (size_t)4194304;
  unsigned short* VB  = stash + (size_t)8388608;
  unsigned short* Wqb = stash + (size_t)12582912;
  unsigned short* Wkb = stash + (size_t)13631488;
  unsigned short* Wvb = stash + (size_t)14680064;

  cvt_all<<<dim3(2560, 3), 256, 0, stream>>>(q, k, v, Wq, Wk, Wv, stash);
  gemm_p<<<dim3(8, 32, 3), 256, 0, stream>>>(QB, KB, VB, Wqb, Wkb, Wvb, QP, KP, VPT);
  attn_rs<<<dim3(512), 256, 0, stream>>>(QP, KP, rsb);
  attn_main<<<dim3(512), 256, 0, stream>>>(QP, KP, VPT, rsb, aw, XB);
  gemm_f<<<dim3(16, 32), 256, 0, stream>>>(XB, Wo, out);
}

// Round 12
// 234.136 us; speedup vs baseline: 1.4303x; 1.0571x over previous
//
#include <hip/hip_runtime.h>
#include <hip/hip_bf16.h>

#define DEVI __device__ __forceinline__

constexpr int kS  = 2048;
constexpr int kH  = 1024;
constexpr int kD  = 64;
constexpr int kBS = 4096;            // B*S
constexpr int kHeadEls = kS * kD;    // elements per (b,head) chunk

typedef __attribute__((ext_vector_type(4))) float f32x4;
typedef __attribute__((ext_vector_type(8))) __bf16 bf16x8;
typedef __attribute__((ext_vector_type(8))) unsigned short u16x8;
typedef __attribute__((ext_vector_type(2))) unsigned int u32x2;

DEVI unsigned short f2bf(float f) {            // RNE fp32 -> bf16
  unsigned int u = __builtin_bit_cast(unsigned int, f);
  u = u + 0x7FFFu + ((u >> 16) & 1u);
  return (unsigned short)(u >> 16);
}
DEVI float fast_exp2(float x) { float r; asm("v_exp_f32 %0, %1" : "=v"(r) : "v"(x)); return r; }
DEVI unsigned int cvt_pk(float lo, float hi) {
  unsigned int r; asm("v_cvt_pk_bf16_f32 %0, %1, %2" : "=v"(r) : "v"(lo), "v"(hi)); return r;
}
DEVI bf16x8 cvt8(const f32x4 a, const f32x4 b) {
  union { unsigned int u[4]; bf16x8 v; } r;
  r.u[0] = cvt_pk(a[0], a[1]); r.u[1] = cvt_pk(a[2], a[3]);
  r.u[2] = cvt_pk(b[0], b[1]); r.u[3] = cvt_pk(b[2], b[3]);
  return r.v;
}
DEVI float bf2f(unsigned int lo16) {           // bf16 (low 16 bits) -> f32
  return __builtin_bit_cast(float, lo16 << 16);
}

#define GLDS16(g, l) __builtin_amdgcn_global_load_lds( \
    (const __attribute__((address_space(1))) void*)(g), \
    (__attribute__((address_space(3))) void*)(l), 16, 0, 0)

#define WAIT_VM(n) do { \
    asm volatile("s_waitcnt vmcnt(" #n ") lgkmcnt(0)" ::: "memory"); \
    __builtin_amdgcn_sched_barrier(0); \
    __builtin_amdgcn_s_barrier(); } while (0)

// ---------------------------------------------------------------------------
// fp32 -> bf16 pre-convert: q,k,v (4M els each) and Wq,Wk,Wv (1M each) into
// the AW-region stash (AW is only written later by attn_fused).
// ---------------------------------------------------------------------------
__global__ __launch_bounds__(256) void cvt_all(
    const float* __restrict__ q, const float* __restrict__ k, const float* __restrict__ v,
    const float* __restrict__ Wq, const float* __restrict__ Wk, const float* __restrict__ Wv,
    unsigned short* __restrict__ stash)
{
  const int z = blockIdx.y, x = blockIdx.x;
  const float* s;
  unsigned short* d;
  size_t i;
  if (x < 2048) {
    s = z == 0 ? q : z == 1 ? k : v;
    d = stash + (size_t)z * 4194304;
    i = ((size_t)x * 256 + threadIdx.x) * 8;
  } else {
    s = z == 0 ? Wq : z == 1 ? Wk : Wv;
    d = stash + (size_t)12582912 + (size_t)z * 1048576;
    i = ((size_t)(x - 2048) * 256 + threadIdx.x) * 8;
  }
  f32x4 a = *(const f32x4*)(s + i);
  f32x4 b = *(const f32x4*)(s + i + 4);
  union { unsigned int u[4]; u16x8 v; } r;
  r.u[0] = cvt_pk(a[0], a[1]); r.u[1] = cvt_pk(a[2], a[3]);
  r.u[2] = cvt_pk(b[0], b[1]); r.u[3] = cvt_pk(b[2], b[3]);
  *(u16x8*)(d + i) = r.v;
}

// ---------------------------------------------------------------------------
// Projection GEMM, all-bf16, RING-3 staging with counted vmcnt (T4):
// prefetch distance 2; per-tile barrier waits vmcnt(4) (retires next tile's
// glds only — they have had ~2 compute phases of slack; newest stay in
// flight). z==2 writes transposed VPT. LDS 48 KB -> 3 blocks/CU.
// ---------------------------------------------------------------------------
__global__ __launch_bounds__(256, 3) void gemm_p(
    const unsigned short* __restrict__ Aq, const unsigned short* __restrict__ Ak,
    const unsigned short* __restrict__ Av,
    const unsigned short* __restrict__ Bq, const unsigned short* __restrict__ Bk,
    const unsigned short* __restrict__ Bv,
    unsigned short* __restrict__ Cq, unsigned short* __restrict__ Ck,
    unsigned short* __restrict__ Cv)
{
  constexpr int K = kH;
  __shared__ __align__(16) unsigned char As[3][8192];
  __shared__ __align__(16) unsigned char Bs[3][8192];

  const int z = blockIdx.z;
  const unsigned short* Ap = z == 0 ? Aq : z == 1 ? Ak : Av;
  const unsigned short* Bp = z == 0 ? Bq : z == 1 ? Bk : Bv;
  unsigned short*       Cp = z == 0 ? Cq : z == 1 ? Ck : Cv;

  const int tid  = threadIdx.x;
  const int lane = tid & 63, wv = tid >> 6;
  const int l15  = lane & 15, lg = lane >> 4;
  const int m0 = blockIdx.y * 128, n0 = blockIdx.x * 128;
  const int wM = (wv & 1) * 64, wN = (wv >> 1) * 64;

  const char* aSrc[2];
  const char* bSrc[2];
#pragma unroll
  for (int c = 0; c < 2; ++c) {
    const int row = c * 64 + (tid >> 2);
    const int cb  = ((tid & 3) * 16) ^ (((row >> 1) & 3) << 4);
    aSrc[c] = (const char*)Ap + ((size_t)(m0 + row) * K) * 2 + cb;
    bSrc[c] = (const char*)Bp + ((size_t)(n0 + row) * K) * 2 + cb;
  }

  int aoff[4], boff[4];
#pragma unroll
  for (int t = 0; t < 4; ++t) {
    const int rA = wM + t * 16 + l15;
    aoff[t] = rA * 64 + ((lg * 16) ^ (((rA >> 1) & 3) << 4));
    const int rB = wN + t * 16 + l15;
    boff[t] = rB * 64 + ((lg * 16) ^ (((rB >> 1) & 3) << 4));
  }

  f32x4 acc[4][4];
#pragma unroll
  for (int i = 0; i < 4; ++i)
#pragma unroll
    for (int j = 0; j < 4; ++j) acc[i][j] = {0.f, 0.f, 0.f, 0.f};

  auto STG = [&](int kk, int bb) {
#pragma unroll
    for (int c = 0; c < 2; ++c) {
      GLDS16(aSrc[c] + (size_t)kk * 2, &As[bb][c * 4096 + wv * 1024]);
      GLDS16(bSrc[c] + (size_t)kk * 2, &Bs[bb][c * 4096 + wv * 1024]);
    }
  };

  STG(0, 0); STG(32, 1);
  WAIT_VM(4);                      // tile0 ready; tile1's 4 glds in flight
  int cur = 0, nx2 = 2;
  for (int t = 0; t < 32; ++t) {
    if (t < 30) STG((t + 2) * 32, nx2);   // overwrites buf read at t-1 (done)
    bf16x8 af[4], bfr[4];
#pragma unroll
    for (int x = 0; x < 4; ++x) {
      af[x]  = *(const bf16x8*)&As[cur][aoff[x]];
      bfr[x] = *(const bf16x8*)&Bs[cur][boff[x]];
    }
#pragma unroll
    for (int mt = 0; mt < 4; ++mt)
#pragma unroll
      for (int nt = 0; nt < 4; ++nt)
        acc[mt][nt] = __builtin_amdgcn_mfma_f32_16x16x32_bf16(af[mt], bfr[nt], acc[mt][nt], 0, 0, 0);
    if (t < 31) {
      if (t < 30) WAIT_VM(4);      // retire next tile's glds; newest fly
      else        WAIT_VM(0);      // tail: last tile must be resident
    }
    cur = cur == 2 ? 0 : cur + 1;
    nx2 = nx2 == 2 ? 0 : nx2 + 1;
  }

  const bool vmode = (z == 2);
#pragma unroll
  for (int mt = 0; mt < 4; ++mt)
#pragma unroll
    for (int nt = 0; nt < 4; ++nt)
#pragma unroll
      for (int r = 0; r < 4; ++r) {
        const int row = m0 + wM + mt * 16 + lg * 4 + r;
        const int col = n0 + wN + nt * 16 + l15;
        const unsigned short hv = f2bf(acc[mt][nt][r]);
        if (!vmode) {
          Cp[(size_t)row * kH + col] = hv;
        } else {
          const int bn = row >> 7;                       // VPT[bn][d][j]
          const int j  = ((row & 127) << 4) | (col >> 6);
          const int d  = col & 63;
          Cp[(size_t)bn * kHeadEls + (size_t)d * kS + j] = hv;
        }
      }
}

// ---------------------------------------------------------------------------
// Final GEMM: out = XB @ Wo^T, tile 128x64, RING-3 + counted vmcnt.
// A bf16, B fp32 (cvt inline), C fp32 nontemporal. LDS 48 KB.
// ---------------------------------------------------------------------------
__global__ __launch_bounds__(256, 3) void gemm_f(
    const unsigned short* __restrict__ Ap, const float* __restrict__ Bp,
    float* __restrict__ Cp)
{
  constexpr int K = kH;
  __shared__ __align__(16) unsigned char As[3][8192];
  __shared__ __align__(16) unsigned char Bs[3][8192];

  const int tid  = threadIdx.x;
  const int lane = tid & 63, wv = tid >> 6;
  const int l15  = lane & 15, lg = lane >> 4;
  const int m0 = blockIdx.y * 128, n0 = blockIdx.x * 64;
  const int wM = (wv & 1) * 64, wN = (wv >> 1) * 32;

  const char* aSrc[2];
#pragma unroll
  for (int c = 0; c < 2; ++c) {
    const int row = c * 64 + (tid >> 2);
    const int cb  = ((tid & 3) * 16) ^ (((row >> 1) & 3) << 4);
    aSrc[c] = (const char*)Ap + ((size_t)(m0 + row) * K) * 2 + cb;
  }
  const char* bSrc[2];
#pragma unroll
  for (int c = 0; c < 2; ++c) {
    const int row = c * 32 + (tid >> 3);
    const int cb  = ((tid & 7) * 16) ^ ((row & 7) << 4);
    bSrc[c] = (const char*)Bp + ((size_t)(n0 + row) * K) * 4 + cb;
  }

  int aoff[4], boff[2];
#pragma unroll
  for (int t = 0; t < 4; ++t) {
    const int rA = wM + t * 16 + l15;
    aoff[t] = rA * 64 + ((lg * 16) ^ (((rA >> 1) & 3) << 4));
  }
#pragma unroll
  for (int t = 0; t < 2; ++t) {
    const int rB = wN + t * 16 + l15;
    boff[t] = rB * 128 + ((lg * 32) ^ ((rB & 7) << 4));
  }

  f32x4 acc[4][2];
#pragma unroll
  for (int i = 0; i < 4; ++i)
#pragma unroll
    for (int j = 0; j < 2; ++j) acc[i][j] = {0.f, 0.f, 0.f, 0.f};

  auto STG = [&](int kk, int bb) {
#pragma unroll
    for (int c = 0; c < 2; ++c) {
      GLDS16(aSrc[c] + (size_t)kk * 2, &As[bb][c * 4096 + wv * 1024]);
      GLDS16(bSrc[c] + (size_t)kk * 4, &Bs[bb][c * 4096 + wv * 1024]);
    }
  };

  STG(0, 0); STG(32, 1);
  WAIT_VM(4);
  int cur = 0, nx2 = 2;
  for (int t = 0; t < 32; ++t) {
    if (t < 30) STG((t + 2) * 32, nx2);
    bf16x8 af[4], bfr[2];
#pragma unroll
    for (int x = 0; x < 4; ++x)
      af[x] = *(const bf16x8*)&As[cur][aoff[x]];
#pragma unroll
    for (int x = 0; x < 2; ++x) {
      f32x4 q0 = *(const f32x4*)&Bs[cur][boff[x]];
      f32x4 q1 = *(const f32x4*)&Bs[cur][boff[x] ^ 16];
      bfr[x] = cvt8(q0, q1);
    }
#pragma unroll
    for (int mt = 0; mt < 4; ++mt)
#pragma unroll
      for (int nt = 0; nt < 2; ++nt)
        acc[mt][nt] = __builtin_amdgcn_mfma_f32_16x16x32_bf16(af[mt], bfr[nt], acc[mt][nt], 0, 0, 0);
    if (t < 31) {
      if (t < 30) WAIT_VM(4);
      else        WAIT_VM(0);
    }
    cur = cur == 2 ? 0 : cur + 1;
    nx2 = nx2 == 2 ? 0 : nx2 + 1;
  }

#pragma unroll
  for (int mt = 0; mt < 4; ++mt)
#pragma unroll
    for (int nt = 0; nt < 2; ++nt)
#pragma unroll
      for (int r = 0; r < 4; ++r) {
        const int row = m0 + wM + mt * 16 + lg * 4 + r;
        const int col = n0 + wN + nt * 16 + l15;
        __builtin_nontemporal_store(acc[mt][nt][r], Cp + (size_t)row * kH + col);
      }
}

// ---------------------------------------------------------------------------
// Fused attention. Pass 1: rs via 128-j K tiles (ring-3, counted vmcnt),
// rs stays in registers (identical summation order -> bit-identical).
// Pass 2: R10's proven AW+PV loop (full-line AW stores via Ws readback,
// dbuf K/V with vmcnt(8)). LDS: 48 KB union. 512 blocks x 4 waves.
// ---------------------------------------------------------------------------
__global__ __launch_bounds__(256, 3) void attn_fused(
    const unsigned short* __restrict__ QP,
    const unsigned short* __restrict__ KP,
    const unsigned short* __restrict__ VPT,
    float* __restrict__ AW,             // [32][2048][2048] fp32
    unsigned short* __restrict__ XB)    // [4096][1024] bf16
{
  // pass 1: 3 x 16 KB K-buffers.  pass 2: Kb[2]@0 (16K) | Vb[2]@16K | Ws@32K
  __shared__ __align__(16) unsigned char SM[49152];

  const int tid  = threadIdx.x;
  const int lane = tid & 63, wv = tid >> 6;
  const int l15  = lane & 15, lg = lane >> 4;
  const int f = blockIdx.x;
  const int x = f & 7, r = f >> 3;
  const int bn = (r >> 4) * 8 + x;      // 4 heads per XCD
  const int i0 = (r & 15) * 128;
  const int b = bn >> 4, n = bn & 15;

  const char* Khb = (const char*)(KP + (size_t)bn * kHeadEls);
  const char* Vhb = (const char*)(VPT + (size_t)bn * kHeadEls);
  const unsigned short* Qh = QP + (size_t)bn * kHeadEls;

  bf16x8 qf[2][2];
#pragma unroll
  for (int m = 0; m < 2; ++m) {
    const int qr = i0 + wv * 32 + m * 16 + l15;
#pragma unroll
    for (int h = 0; h < 2; ++h)
      qf[m][h] = *(const bf16x8*)(Qh + (size_t)qr * kD + h * 32 + lg * 8);
  }
  const float cexp = 0.18033688011112042f;   // log2(e)/8

  // ================= pass 1: row sums (128-j tiles, ring-3) =================
  int kb1[4];
#pragma unroll
  for (int p = 0; p < 4; ++p) {
    const int row = p * 32 + (tid >> 3);
    kb1[p] = row * 128 + (((tid & 7) * 16) ^ ((row & 7) << 4));
  }
  auto STAGE1 = [&](int j0, int bb) {
#pragma unroll
    for (int p = 0; p < 4; ++p)
      GLDS16(Khb + (size_t)j0 * 128 + kb1[p], SM + bb * 16384 + p * 4096 + tid * 16);
  };

  float rs[2] = {0.f, 0.f};
  STAGE1(0, 0); STAGE1(128, 1);
  WAIT_VM(4);
  int c1 = 0, n1 = 2;
  for (int t = 0; t < 16; ++t) {
    if (t < 14) STAGE1((t + 2) * 128, n1);
    const char* kb = (const char*)SM + c1 * 16384;
#pragma unroll
    for (int ct = 0; ct < 8; ++ct) {
      const int rK = ct * 16 + l15;
      const int sw = (rK & 7) << 4;
      const bf16x8 k0 = *(const bf16x8*)(kb + rK * 128 + ((lg * 16) ^ sw));
      const bf16x8 k1 = *(const bf16x8*)(kb + rK * 128 + ((64 + lg * 16) ^ sw));
#pragma unroll
      for (int m = 0; m < 2; ++m) {
        f32x4 s = {0.f, 0.f, 0.f, 0.f};
        s = __builtin_amdgcn_mfma_f32_16x16x32_bf16(k0, qf[m][0], s, 0, 0, 0);
        s = __builtin_amdgcn_mfma_f32_16x16x32_bf16(k1, qf[m][1], s, 0, 0, 0);
        const float w0 = fast_exp2(s[0] * cexp), w1 = fast_exp2(s[1] * cexp);
        const float w2 = fast_exp2(s[2] * cexp), w3 = fast_exp2(s[3] * cexp);
        rs[m] += (w0 + w1) + (w2 + w3);
      }
    }
    if (t < 15) {
      if (t < 14) WAIT_VM(4);
      else        WAIT_VM(0);
    }
    c1 = c1 == 2 ? 0 : c1 + 1;
    n1 = n1 == 2 ? 0 : n1 + 1;
  }
#pragma unroll
  for (int m = 0; m < 2; ++m) {
    rs[m] += __shfl_xor(rs[m], 16, 64);
    rs[m] += __shfl_xor(rs[m], 32, 64);
  }
  float inv[2];
#pragma unroll
  for (int m = 0; m < 2; ++m) inv[m] = 1.0f / rs[m];

  __syncthreads();   // all pass-1 LDS reads done before pass-2 staging

  // ================= pass 2: AW + PV (R10-proven loop) =================
  char* const Kb2 = (char*)SM;            // 2 x 8 KB
  char* const Vb2 = (char*)SM + 16384;    // 2 x 8 KB
  char* const Wsb = (char*)SM + 32768;    // 16 KB

  int kbase[2], vbase[2];
#pragma unroll
  for (int p = 0; p < 2; ++p) {
    const int row = p * 32 + (tid >> 3);
    const int sw  = ((tid & 7) * 16) ^ ((row & 7) << 4);
    kbase[p] = row * 128 + sw;          // K: row = j
    vbase[p] = row * 4096 + sw;         // V: row = d (VPT row stride 4096 B)
  }
  auto STAGE_KV = [&](int j0, int bb) {
#pragma unroll
    for (int p = 0; p < 2; ++p) {
      GLDS16(Khb + (size_t)j0 * 128 + kbase[p], Kb2 + bb * 8192 + p * 4096 + tid * 16);
      GLDS16(Vhb + (size_t)j0 * 2 + vbase[p],   Vb2 + bb * 8192 + p * 4096 + tid * 16);
    }
  };

  int koff[4][2], voff[2][4], wswr[2][4], wsrd[2][2];
#pragma unroll
  for (int ct = 0; ct < 4; ++ct) {
    const int rK = ct * 16 + l15;
#pragma unroll
    for (int h = 0; h < 2; ++h)
      koff[ct][h] = rK * 128 + ((h * 64 + lg * 16) ^ ((rK & 7) << 4));
  }
#pragma unroll
  for (int jc = 0; jc < 2; ++jc)
#pragma unroll
    for (int dt = 0; dt < 4; ++dt) {
      const int d = dt * 16 + l15;
      voff[jc][dt] = d * 128 + ((jc * 64 + lg * 16) ^ ((d & 7) << 4));
    }
#pragma unroll
  for (int m = 0; m < 2; ++m) {
    const int rw = wv * 32 + m * 16 + l15;
#pragma unroll
    for (int ct = 0; ct < 4; ++ct)
      wswr[m][ct] = rw * 128 + ((ct * 32 + lg * 8) ^ ((rw & 7) << 4));
#pragma unroll
    for (int jc = 0; jc < 2; ++jc)
      wsrd[m][jc] = rw * 128 + ((jc * 64 + lg * 16) ^ ((rw & 7) << 4));
  }

  int awrd[8];
  float* awp[8];
#pragma unroll
  for (int u = 0; u < 8; ++u) {
    const int rw = wv * 32 + u * 4 + lg;
    awrd[u] = rw * 128 + ((l15 * 8) ^ ((rw & 7) << 4));
    awp[u]  = AW + ((size_t)bn * kS + i0 + rw) * kS + l15 * 4;
  }

  f32x4 pv[2][4];
#pragma unroll
  for (int m = 0; m < 2; ++m)
#pragma unroll
    for (int dt = 0; dt < 4; ++dt) pv[m][dt] = {0.f, 0.f, 0.f, 0.f};

  STAGE_KV(0, 0);
  WAIT_VM(0);

  int cur = 0;
  for (int t = 0; t < 32; ++t) {
    if (t < 31) STAGE_KV((t + 1) * 64, cur ^ 1);   // 4 glds, oldest in queue
    __builtin_amdgcn_sched_barrier(0);             // pin glds before AW stores
#pragma unroll
    for (int ct = 0; ct < 4; ++ct) {
      const bf16x8 kb0 = *(const bf16x8*)(Kb2 + cur * 8192 + koff[ct][0]);
      const bf16x8 kb1 = *(const bf16x8*)(Kb2 + cur * 8192 + koff[ct][1]);
#pragma unroll
      for (int m = 0; m < 2; ++m) {
        f32x4 s = {0.f, 0.f, 0.f, 0.f};
        s = __builtin_amdgcn_mfma_f32_16x16x32_bf16(kb0, qf[m][0], s, 0, 0, 0);
        s = __builtin_amdgcn_mfma_f32_16x16x32_bf16(kb1, qf[m][1], s, 0, 0, 0);
        f32x4 w;
#pragma unroll
        for (int r2 = 0; r2 < 4; ++r2) w[r2] = fast_exp2(s[r2] * cexp) * inv[m];
        u32x2 pk; pk[0] = cvt_pk(w[0], w[1]); pk[1] = cvt_pk(w[2], w[3]);
        *(u32x2*)(Wsb + wswr[m][ct]) = pk;   // wave-private rows
      }
    }
#pragma unroll
    for (int jc = 0; jc < 2; ++jc) {
      const bf16x8 pa0 = *(const bf16x8*)(Wsb + wsrd[0][jc]);
      const bf16x8 pa1 = *(const bf16x8*)(Wsb + wsrd[1][jc]);
#pragma unroll
      for (int dt = 0; dt < 4; ++dt) {
        const bf16x8 vf = *(const bf16x8*)(Vb2 + cur * 8192 + voff[jc][dt]);
        pv[0][dt] = __builtin_amdgcn_mfma_f32_16x16x32_bf16(pa0, vf, pv[0][dt], 0, 0, 0);
        pv[1][dt] = __builtin_amdgcn_mfma_f32_16x16x32_bf16(pa1, vf, pv[1][dt], 0, 0, 0);
      }
    }
    // AW stores: Ws readback row-contiguous -> full-line store instrs
#pragma unroll
    for (int u = 0; u < 8; ++u) {
      const u32x2 pk = *(const u32x2*)(Wsb + awrd[u]);
      f32x4 w;
      w[0] = bf2f(pk[0] & 0xFFFFu);
      w[1] = bf2f(pk[0] >> 16);
      w[2] = bf2f(pk[1] & 0xFFFFu);
      w[3] = bf2f(pk[1] >> 16);
      __builtin_nontemporal_store(w, (f32x4*)(awp[u] + t * 64));
    }
    if (t < 31) WAIT_VM(8);   // retire this tile's 4 glds; 8 stores keep flying
    cur ^= 1;
  }

  // XB epilogue: PV already normalized
#pragma unroll
  for (int m = 0; m < 2; ++m)
#pragma unroll
    for (int dt = 0; dt < 4; ++dt)
#pragma unroll
      for (int r2 = 0; r2 < 4; ++r2) {
        const int row = b * kS + i0 + wv * 32 + m * 16 + lg * 4 + r2;  // (b,i)
        const int col = n * 64 + dt * 16 + l15;                        // (n d)
        XB[(size_t)row * kH + col] = f2bf(pv[m][dt][r2]);
      }
}

// ---------------------------------------------------------------------------
extern "C" void kernel_launch(void* const* d_in, const int* in_sizes, int n_in,
                              void* d_out, int out_size, void* d_ws, size_t ws_size,
                              hipStream_t stream) {
  const float* q  = (const float*)d_in[0];
  const float* k  = (const float*)d_in[1];
  const float* v  = (const float*)d_in[2];
  const float* Wq = (const float*)d_in[3];
  const float* Wk = (const float*)d_in[4];
  const float* Wv = (const float*)d_in[5];
  const float* Wo = (const float*)d_in[6];

  float* out = (float*)d_out;
  float* aw  = out + (size_t)kBS * kH;

  unsigned short* QP  = (unsigned short*)d_ws;         // 8 MB
  unsigned short* KP  = QP  + (size_t)kBS * kH;        // 8 MB
  unsigned short* VPT = KP  + (size_t)kBS * kH;        // 8 MB
  unsigned short* XB  = VPT + (size_t)kBS * kH;        // 8 MB (total 32 MB)

  // bf16 stash in AW region: consumed by gemm_p before attn_fused writes AW
  unsigned short* stash = (unsigned short*)aw;
  unsigned short* QB  = stash;
  unsigned short* KB  = stash + (size_t)4194304;
  unsigned short* VB  = stash + (size_t)8388608;
  unsigned short* Wqb = stash + (size_t)12582912;
  unsigned short* Wkb = stash + (size_t)13631488;
  unsigned short* Wvb = stash + (size_t)14680064;

  cvt_all<<<dim3(2560, 3), 256, 0, stream>>>(q, k, v, Wq, Wk, Wv, stash);
  gemm_p<<<dim3(8, 32, 3), 256, 0, stream>>>(QB, KB, VB, Wqb, Wkb, Wvb, QP, KP, VPT);
  attn_fused<<<dim3(512), 256, 0, stream>>>(QP, KP, VPT, aw, XB);
  gemm_f<<<dim3(16, 32), 256, 0, stream>>>(XB, Wo, out);
}

// Round 13
// 229.981 us; speedup vs baseline: 1.4561x; 1.0181x over previous
//
#include <hip/hip_runtime.h>
#include <hip/hip_bf16.h>

#define DEVI __device__ __forceinline__

constexpr int kS  = 2048;
constexpr int kH  = 1024;
constexpr int kD  = 64;
constexpr int kBS = 4096;            // B*S
constexpr int kHeadEls = kS * kD;    // elements per (b,head) chunk

typedef __attribute__((ext_vector_type(4))) float f32x4;
typedef __attribute__((ext_vector_type(8))) __bf16 bf16x8;
typedef __attribute__((ext_vector_type(8))) unsigned short u16x8;
typedef __attribute__((ext_vector_type(2))) unsigned int u32x2;

DEVI unsigned short f2bf(float f) {            // RNE fp32 -> bf16
  unsigned int u = __builtin_bit_cast(unsigned int, f);
  u = u + 0x7FFFu + ((u >> 16) & 1u);
  return (unsigned short)(u >> 16);
}
DEVI float fast_exp2(float x) { float r; asm("v_exp_f32 %0, %1" : "=v"(r) : "v"(x)); return r; }
DEVI unsigned int cvt_pk(float lo, float hi) {
  unsigned int r; asm("v_cvt_pk_bf16_f32 %0, %1, %2" : "=v"(r) : "v"(lo), "v"(hi)); return r;
}
DEVI bf16x8 cvt8(const f32x4 a, const f32x4 b) {
  union { unsigned int u[4]; bf16x8 v; } r;
  r.u[0] = cvt_pk(a[0], a[1]); r.u[1] = cvt_pk(a[2], a[3]);
  r.u[2] = cvt_pk(b[0], b[1]); r.u[3] = cvt_pk(b[2], b[3]);
  return r.v;
}
DEVI float bf2f(unsigned int lo16) {           // bf16 (low 16 bits) -> f32
  return __builtin_bit_cast(float, lo16 << 16);
}

#define GLDS16(g, l) __builtin_amdgcn_global_load_lds( \
    (const __attribute__((address_space(1))) void*)(g), \
    (__attribute__((address_space(3))) void*)(l), 16, 0, 0)

#define WAIT_VM(n) do { \
    asm volatile("s_waitcnt vmcnt(" #n ") lgkmcnt(0)" ::: "memory"); \
    __builtin_amdgcn_sched_barrier(0); \
    __builtin_amdgcn_s_barrier(); } while (0)

// ---------------------------------------------------------------------------
// fp32 -> bf16 pre-convert: q,k,v (4M els each) and Wq,Wk,Wv (1M each) into
// the AW-region stash (AW is only written later by attn_fused).
// ---------------------------------------------------------------------------
__global__ __launch_bounds__(256) void cvt_all(
    const float* __restrict__ q, const float* __restrict__ k, const float* __restrict__ v,
    const float* __restrict__ Wq, const float* __restrict__ Wk, const float* __restrict__ Wv,
    unsigned short* __restrict__ stash)
{
  const int z = blockIdx.y, x = blockIdx.x;
  const float* s;
  unsigned short* d;
  size_t i;
  if (x < 2048) {
    s = z == 0 ? q : z == 1 ? k : v;
    d = stash + (size_t)z * 4194304;
    i = ((size_t)x * 256 + threadIdx.x) * 8;
  } else {
    s = z == 0 ? Wq : z == 1 ? Wk : Wv;
    d = stash + (size_t)12582912 + (size_t)z * 1048576;
    i = ((size_t)(x - 2048) * 256 + threadIdx.x) * 8;
  }
  f32x4 a = *(const f32x4*)(s + i);
  f32x4 b = *(const f32x4*)(s + i + 4);
  union { unsigned int u[4]; u16x8 v; } r;
  r.u[0] = cvt_pk(a[0], a[1]); r.u[1] = cvt_pk(a[2], a[3]);
  r.u[2] = cvt_pk(b[0], b[1]); r.u[3] = cvt_pk(b[2], b[3]);
  *(u16x8*)(d + i) = r.v;
}

// ---------------------------------------------------------------------------
// Projection GEMM, all-bf16, RING-3 + counted vmcnt (R12-proven loop).
// NEW: 1-D grid 768 with XCD-locality mapping — the 8 n-blocks sharing one
// A-row-panel get identical b%8, so they land on one XCD's L2 (A fetched
// once per panel, not 8x). b = x*96 + (z*32 + y).
// ---------------------------------------------------------------------------
__global__ __launch_bounds__(256, 3) void gemm_p(
    const unsigned short* __restrict__ Aq, const unsigned short* __restrict__ Ak,
    const unsigned short* __restrict__ Av,
    const unsigned short* __restrict__ Bq, const unsigned short* __restrict__ Bk,
    const unsigned short* __restrict__ Bv,
    unsigned short* __restrict__ Cq, unsigned short* __restrict__ Ck,
    unsigned short* __restrict__ Cv)
{
  constexpr int K = kH;
  __shared__ __align__(16) unsigned char As[3][8192];
  __shared__ __align__(16) unsigned char Bs[3][8192];

  const int bId = blockIdx.x;          // 0..767
  const int c   = bId % 96;
  const int xb  = bId / 96;            // n-block 0..7
  const int yb  = c & 31;              // m-block 0..31  (XCD = bId%8 = yb%8)
  const int z   = c >> 5;              // 0..2

  const unsigned short* Ap = z == 0 ? Aq : z == 1 ? Ak : Av;
  const unsigned short* Bp = z == 0 ? Bq : z == 1 ? Bk : Bv;
  unsigned short*       Cp = z == 0 ? Cq : z == 1 ? Ck : Cv;

  const int tid  = threadIdx.x;
  const int lane = tid & 63, wv = tid >> 6;
  const int l15  = lane & 15, lg = lane >> 4;
  const int m0 = yb * 128, n0 = xb * 128;
  const int wM = (wv & 1) * 64, wN = (wv >> 1) * 64;

  const char* aSrc[2];
  const char* bSrc[2];
#pragma unroll
  for (int cc = 0; cc < 2; ++cc) {
    const int row = cc * 64 + (tid >> 2);
    const int cb  = ((tid & 3) * 16) ^ (((row >> 1) & 3) << 4);
    aSrc[cc] = (const char*)Ap + ((size_t)(m0 + row) * K) * 2 + cb;
    bSrc[cc] = (const char*)Bp + ((size_t)(n0 + row) * K) * 2 + cb;
  }

  int aoff[4], boff[4];
#pragma unroll
  for (int t = 0; t < 4; ++t) {
    const int rA = wM + t * 16 + l15;
    aoff[t] = rA * 64 + ((lg * 16) ^ (((rA >> 1) & 3) << 4));
    const int rB = wN + t * 16 + l15;
    boff[t] = rB * 64 + ((lg * 16) ^ (((rB >> 1) & 3) << 4));
  }

  f32x4 acc[4][4];
#pragma unroll
  for (int i = 0; i < 4; ++i)
#pragma unroll
    for (int j = 0; j < 4; ++j) acc[i][j] = {0.f, 0.f, 0.f, 0.f};

  auto STG = [&](int kk, int bb) {
#pragma unroll
    for (int cc = 0; cc < 2; ++cc) {
      GLDS16(aSrc[cc] + (size_t)kk * 2, &As[bb][cc * 4096 + wv * 1024]);
      GLDS16(bSrc[cc] + (size_t)kk * 2, &Bs[bb][cc * 4096 + wv * 1024]);
    }
  };

  STG(0, 0); STG(32, 1);
  WAIT_VM(4);                      // tile0 ready; tile1's 4 glds in flight
  int cur = 0, nx2 = 2;
  for (int t = 0; t < 32; ++t) {
    if (t < 30) STG((t + 2) * 32, nx2);
    bf16x8 af[4], bfr[4];
#pragma unroll
    for (int x = 0; x < 4; ++x) {
      af[x]  = *(const bf16x8*)&As[cur][aoff[x]];
      bfr[x] = *(const bf16x8*)&Bs[cur][boff[x]];
    }
#pragma unroll
    for (int mt = 0; mt < 4; ++mt)
#pragma unroll
      for (int nt = 0; nt < 4; ++nt)
        acc[mt][nt] = __builtin_amdgcn_mfma_f32_16x16x32_bf16(af[mt], bfr[nt], acc[mt][nt], 0, 0, 0);
    if (t < 31) {
      if (t < 30) WAIT_VM(4);
      else        WAIT_VM(0);
    }
    cur = cur == 2 ? 0 : cur + 1;
    nx2 = nx2 == 2 ? 0 : nx2 + 1;
  }

  const bool vmode = (z == 2);
#pragma unroll
  for (int mt = 0; mt < 4; ++mt)
#pragma unroll
    for (int nt = 0; nt < 4; ++nt)
#pragma unroll
      for (int r = 0; r < 4; ++r) {
        const int row = m0 + wM + mt * 16 + lg * 4 + r;
        const int col = n0 + wN + nt * 16 + l15;
        const unsigned short hv = f2bf(acc[mt][nt][r]);
        if (!vmode) {
          Cp[(size_t)row * kH + col] = hv;
        } else {
          const int bn = row >> 7;                       // VPT[bn][d][j]
          const int j  = ((row & 127) << 4) | (col >> 6);
          const int d  = col & 63;
          Cp[(size_t)bn * kHeadEls + (size_t)d * kS + j] = hv;
        }
      }
}

// ---------------------------------------------------------------------------
// Final GEMM: out = XB @ Wo^T, tile 128x64, RING-3 + counted vmcnt.
// NEW: 1-D grid 512, b = x*32 + y -> the 16 n-blocks sharing one XB panel
// get identical b%8 (= y%8) -> one XCD per panel (XB fetched once, not 16x).
// ---------------------------------------------------------------------------
__global__ __launch_bounds__(256, 3) void gemm_f(
    const unsigned short* __restrict__ Ap, const float* __restrict__ Bp,
    float* __restrict__ Cp)
{
  constexpr int K = kH;
  __shared__ __align__(16) unsigned char As[3][8192];
  __shared__ __align__(16) unsigned char Bs[3][8192];

  const int bId = blockIdx.x;          // 0..511
  const int yb  = bId & 31;            // m-block (XCD = bId%8 = yb%8)
  const int xb  = bId >> 5;            // n-block 0..15

  const int tid  = threadIdx.x;
  const int lane = tid & 63, wv = tid >> 6;
  const int l15  = lane & 15, lg = lane >> 4;
  const int m0 = yb * 128, n0 = xb * 64;
  const int wM = (wv & 1) * 64, wN = (wv >> 1) * 32;

  const char* aSrc[2];
#pragma unroll
  for (int c = 0; c < 2; ++c) {
    const int row = c * 64 + (tid >> 2);
    const int cb  = ((tid & 3) * 16) ^ (((row >> 1) & 3) << 4);
    aSrc[c] = (const char*)Ap + ((size_t)(m0 + row) * K) * 2 + cb;
  }
  const char* bSrc[2];
#pragma unroll
  for (int c = 0; c < 2; ++c) {
    const int row = c * 32 + (tid >> 3);
    const int cb  = ((tid & 7) * 16) ^ ((row & 7) << 4);
    bSrc[c] = (const char*)Bp + ((size_t)(n0 + row) * K) * 4 + cb;
  }

  int aoff[4], boff[2];
#pragma unroll
  for (int t = 0; t < 4; ++t) {
    const int rA = wM + t * 16 + l15;
    aoff[t] = rA * 64 + ((lg * 16) ^ (((rA >> 1) & 3) << 4));
  }
#pragma unroll
  for (int t = 0; t < 2; ++t) {
    const int rB = wN + t * 16 + l15;
    boff[t] = rB * 128 + ((lg * 32) ^ ((rB & 7) << 4));
  }

  f32x4 acc[4][2];
#pragma unroll
  for (int i = 0; i < 4; ++i)
#pragma unroll
    for (int j = 0; j < 2; ++j) acc[i][j] = {0.f, 0.f, 0.f, 0.f};

  auto STG = [&](int kk, int bb) {
#pragma unroll
    for (int c = 0; c < 2; ++c) {
      GLDS16(aSrc[c] + (size_t)kk * 2, &As[bb][c * 4096 + wv * 1024]);
      GLDS16(bSrc[c] + (size_t)kk * 4, &Bs[bb][c * 4096 + wv * 1024]);
    }
  };

  STG(0, 0); STG(32, 1);
  WAIT_VM(4);
  int cur = 0, nx2 = 2;
  for (int t = 0; t < 32; ++t) {
    if (t < 30) STG((t + 2) * 32, nx2);
    bf16x8 af[4], bfr[2];
#pragma unroll
    for (int x = 0; x < 4; ++x)
      af[x] = *(const bf16x8*)&As[cur][aoff[x]];
#pragma unroll
    for (int x = 0; x < 2; ++x) {
      f32x4 q0 = *(const f32x4*)&Bs[cur][boff[x]];
      f32x4 q1 = *(const f32x4*)&Bs[cur][boff[x] ^ 16];
      bfr[x] = cvt8(q0, q1);
    }
#pragma unroll
    for (int mt = 0; mt < 4; ++mt)
#pragma unroll
      for (int nt = 0; nt < 2; ++nt)
        acc[mt][nt] = __builtin_amdgcn_mfma_f32_16x16x32_bf16(af[mt], bfr[nt], acc[mt][nt], 0, 0, 0);
    if (t < 31) {
      if (t < 30) WAIT_VM(4);
      else        WAIT_VM(0);
    }
    cur = cur == 2 ? 0 : cur + 1;
    nx2 = nx2 == 2 ? 0 : nx2 + 1;
  }

#pragma unroll
  for (int mt = 0; mt < 4; ++mt)
#pragma unroll
    for (int nt = 0; nt < 2; ++nt)
#pragma unroll
      for (int r = 0; r < 4; ++r) {
        const int row = m0 + wM + mt * 16 + lg * 4 + r;
        const int col = n0 + wN + nt * 16 + l15;
        __builtin_nontemporal_store(acc[mt][nt][r], Cp + (size_t)row * kH + col);
      }
}

// ---------------------------------------------------------------------------
// Fused attention (R12-proven, unchanged). Pass 1: rs via 128-j K ring-3.
// Pass 2: AW (full-line stores via Ws readback) + PV, dbuf K/V, vmcnt(8).
// ---------------------------------------------------------------------------
__global__ __launch_bounds__(256, 3) void attn_fused(
    const unsigned short* __restrict__ QP,
    const unsigned short* __restrict__ KP,
    const unsigned short* __restrict__ VPT,
    float* __restrict__ AW,             // [32][2048][2048] fp32
    unsigned short* __restrict__ XB)    // [4096][1024] bf16
{
  // pass 1: 3 x 16 KB K-buffers.  pass 2: Kb[2]@0 (16K) | Vb[2]@16K | Ws@32K
  __shared__ __align__(16) unsigned char SM[49152];

  const int tid  = threadIdx.x;
  const int lane = tid & 63, wv = tid >> 6;
  const int l15  = lane & 15, lg = lane >> 4;
  const int f = blockIdx.x;
  const int x = f & 7, r = f >> 3;
  const int bn = (r >> 4) * 8 + x;      // 4 heads per XCD
  const int i0 = (r & 15) * 128;
  const int b = bn >> 4, n = bn & 15;

  const char* Khb = (const char*)(KP + (size_t)bn * kHeadEls);
  const char* Vhb = (const char*)(VPT + (size_t)bn * kHeadEls);
  const unsigned short* Qh = QP + (size_t)bn * kHeadEls;

  bf16x8 qf[2][2];
#pragma unroll
  for (int m = 0; m < 2; ++m) {
    const int qr = i0 + wv * 32 + m * 16 + l15;
#pragma unroll
    for (int h = 0; h < 2; ++h)
      qf[m][h] = *(const bf16x8*)(Qh + (size_t)qr * kD + h * 32 + lg * 8);
  }
  const float cexp = 0.18033688011112042f;   // log2(e)/8

  // ================= pass 1: row sums (128-j tiles, ring-3) =================
  int kb1[4];
#pragma unroll
  for (int p = 0; p < 4; ++p) {
    const int row = p * 32 + (tid >> 3);
    kb1[p] = row * 128 + (((tid & 7) * 16) ^ ((row & 7) << 4));
  }
  auto STAGE1 = [&](int j0, int bb) {
#pragma unroll
    for (int p = 0; p < 4; ++p)
      GLDS16(Khb + (size_t)j0 * 128 + kb1[p], SM + bb * 16384 + p * 4096 + tid * 16);
  };

  float rs[2] = {0.f, 0.f};
  STAGE1(0, 0); STAGE1(128, 1);
  WAIT_VM(4);
  int c1 = 0, n1 = 2;
  for (int t = 0; t < 16; ++t) {
    if (t < 14) STAGE1((t + 2) * 128, n1);
    const char* kb = (const char*)SM + c1 * 16384;
#pragma unroll
    for (int ct = 0; ct < 8; ++ct) {
      const int rK = ct * 16 + l15;
      const int sw = (rK & 7) << 4;
      const bf16x8 k0 = *(const bf16x8*)(kb + rK * 128 + ((lg * 16) ^ sw));
      const bf16x8 k1 = *(const bf16x8*)(kb + rK * 128 + ((64 + lg * 16) ^ sw));
#pragma unroll
      for (int m = 0; m < 2; ++m) {
        f32x4 s = {0.f, 0.f, 0.f, 0.f};
        s = __builtin_amdgcn_mfma_f32_16x16x32_bf16(k0, qf[m][0], s, 0, 0, 0);
        s = __builtin_amdgcn_mfma_f32_16x16x32_bf16(k1, qf[m][1], s, 0, 0, 0);
        const float w0 = fast_exp2(s[0] * cexp), w1 = fast_exp2(s[1] * cexp);
        const float w2 = fast_exp2(s[2] * cexp), w3 = fast_exp2(s[3] * cexp);
        rs[m] += (w0 + w1) + (w2 + w3);
      }
    }
    if (t < 15) {
      if (t < 14) WAIT_VM(4);
      else        WAIT_VM(0);
    }
    c1 = c1 == 2 ? 0 : c1 + 1;
    n1 = n1 == 2 ? 0 : n1 + 1;
  }
#pragma unroll
  for (int m = 0; m < 2; ++m) {
    rs[m] += __shfl_xor(rs[m], 16, 64);
    rs[m] += __shfl_xor(rs[m], 32, 64);
  }
  float inv[2];
#pragma unroll
  for (int m = 0; m < 2; ++m) inv[m] = 1.0f / rs[m];

  __syncthreads();   // all pass-1 LDS reads done before pass-2 staging

  // ================= pass 2: AW + PV =================
  char* const Kb2 = (char*)SM;            // 2 x 8 KB
  char* const Vb2 = (char*)SM + 16384;    // 2 x 8 KB
  char* const Wsb = (char*)SM + 32768;    // 16 KB

  int kbase[2], vbase[2];
#pragma unroll
  for (int p = 0; p < 2; ++p) {
    const int row = p * 32 + (tid >> 3);
    const int sw  = ((tid & 7) * 16) ^ ((row & 7) << 4);
    kbase[p] = row * 128 + sw;          // K: row = j
    vbase[p] = row * 4096 + sw;         // V: row = d (VPT row stride 4096 B)
  }
  auto STAGE_KV = [&](int j0, int bb) {
#pragma unroll
    for (int p = 0; p < 2; ++p) {
      GLDS16(Khb + (size_t)j0 * 128 + kbase[p], Kb2 + bb * 8192 + p * 4096 + tid * 16);
      GLDS16(Vhb + (size_t)j0 * 2 + vbase[p],   Vb2 + bb * 8192 + p * 4096 + tid * 16);
    }
  };

  int koff[4][2], voff[2][4], wswr[2][4], wsrd[2][2];
#pragma unroll
  for (int ct = 0; ct < 4; ++ct) {
    const int rK = ct * 16 + l15;
#pragma unroll
    for (int h = 0; h < 2; ++h)
      koff[ct][h] = rK * 128 + ((h * 64 + lg * 16) ^ ((rK & 7) << 4));
  }
#pragma unroll
  for (int jc = 0; jc < 2; ++jc)
#pragma unroll
    for (int dt = 0; dt < 4; ++dt) {
      const int d = dt * 16 + l15;
      voff[jc][dt] = d * 128 + ((jc * 64 + lg * 16) ^ ((d & 7) << 4));
    }
#pragma unroll
  for (int m = 0; m < 2; ++m) {
    const int rw = wv * 32 + m * 16 + l15;
#pragma unroll
    for (int ct = 0; ct < 4; ++ct)
      wswr[m][ct] = rw * 128 + ((ct * 32 + lg * 8) ^ ((rw & 7) << 4));
#pragma unroll
    for (int jc = 0; jc < 2; ++jc)
      wsrd[m][jc] = rw * 128 + ((jc * 64 + lg * 16) ^ ((rw & 7) << 4));
  }

  int awrd[8];
  float* awp[8];
#pragma unroll
  for (int u = 0; u < 8; ++u) {
    const int rw = wv * 32 + u * 4 + lg;
    awrd[u] = rw * 128 + ((l15 * 8) ^ ((rw & 7) << 4));
    awp[u]  = AW + ((size_t)bn * kS + i0 + rw) * kS + l15 * 4;
  }

  f32x4 pv[2][4];
#pragma unroll
  for (int m = 0; m < 2; ++m)
#pragma unroll
    for (int dt = 0; dt < 4; ++dt) pv[m][dt] = {0.f, 0.f, 0.f, 0.f};

  STAGE_KV(0, 0);
  WAIT_VM(0);

  int cur = 0;
  for (int t = 0; t < 32; ++t) {
    if (t < 31) STAGE_KV((t + 1) * 64, cur ^ 1);   // 4 glds, oldest in queue
    __builtin_amdgcn_sched_barrier(0);             // pin glds before AW stores
#pragma unroll
    for (int ct = 0; ct < 4; ++ct) {
      const bf16x8 kb0 = *(const bf16x8*)(Kb2 + cur * 8192 + koff[ct][0]);
      const bf16x8 kb1 = *(const bf16x8*)(Kb2 + cur * 8192 + koff[ct][1]);
#pragma unroll
      for (int m = 0; m < 2; ++m) {
        f32x4 s = {0.f, 0.f, 0.f, 0.f};
        s = __builtin_amdgcn_mfma_f32_16x16x32_bf16(kb0, qf[m][0], s, 0, 0, 0);
        s = __builtin_amdgcn_mfma_f32_16x16x32_bf16(kb1, qf[m][1], s, 0, 0, 0);
        f32x4 w;
#pragma unroll
        for (int r2 = 0; r2 < 4; ++r2) w[r2] = fast_exp2(s[r2] * cexp) * inv[m];
        u32x2 pk; pk[0] = cvt_pk(w[0], w[1]); pk[1] = cvt_pk(w[2], w[3]);
        *(u32x2*)(Wsb + wswr[m][ct]) = pk;   // wave-private rows
      }
    }
#pragma unroll
    for (int jc = 0; jc < 2; ++jc) {
      const bf16x8 pa0 = *(const bf16x8*)(Wsb + wsrd[0][jc]);
      const bf16x8 pa1 = *(const bf16x8*)(Wsb + wsrd[1][jc]);
#pragma unroll
      for (int dt = 0; dt < 4; ++dt) {
        const bf16x8 vf = *(const bf16x8*)(Vb2 + cur * 8192 + voff[jc][dt]);
        pv[0][dt] = __builtin_amdgcn_mfma_f32_16x16x32_bf16(pa0, vf, pv[0][dt], 0, 0, 0);
        pv[1][dt] = __builtin_amdgcn_mfma_f32_16x16x32_bf16(pa1, vf, pv[1][dt], 0, 0, 0);
      }
    }
    // AW stores: Ws readback row-contiguous -> full-line store instrs
#pragma unroll
    for (int u = 0; u < 8; ++u) {
      const u32x2 pk = *(const u32x2*)(Wsb + awrd[u]);
      f32x4 w;
      w[0] = bf2f(pk[0] & 0xFFFFu);
      w[1] = bf2f(pk[0] >> 16);
      w[2] = bf2f(pk[1] & 0xFFFFu);
      w[3] = bf2f(pk[1] >> 16);
      __builtin_nontemporal_store(w, (f32x4*)(awp[u] + t * 64));
    }
    if (t < 31) WAIT_VM(8);   // retire this tile's 4 glds; 8 stores keep flying
    cur ^= 1;
  }

  // XB epilogue: PV already normalized
#pragma unroll
  for (int m = 0; m < 2; ++m)
#pragma unroll
    for (int dt = 0; dt < 4; ++dt)
#pragma unroll
      for (int r2 = 0; r2 < 4; ++r2) {
        const int row = b * kS + i0 + wv * 32 + m * 16 + lg * 4 + r2;  // (b,i)
        const int col = n * 64 + dt * 16 + l15;                        // (n d)
        XB[(size_t)row * kH + col] = f2bf(pv[m][dt][r2]);
      }
}

// ---------------------------------------------------------------------------
extern "C" void kernel_launch(void* const* d_in, const int* in_sizes, int n_in,
                              void* d_out, int out_size, void* d_ws, size_t ws_size,
                              hipStream_t stream) {
  const float* q  = (const float*)d_in[0];
  const float* k  = (const float*)d_in[1];
  const float* v  = (const float*)d_in[2];
  const float* Wq = (const float*)d_in[3];
  const float* Wk = (const float*)d_in[4];
  const float* Wv = (const float*)d_in[5];
  const float* Wo = (const float*)d_in[6];

  float* out = (float*)d_out;
  float* aw  = out + (size_t)kBS * kH;

  unsigned short* QP  = (unsigned short*)d_ws;         // 8 MB
  unsigned short* KP  = QP  + (size_t)kBS * kH;        // 8 MB
  unsigned short* VPT = KP  + (size_t)kBS * kH;        // 8 MB
  unsigned short* XB  = VPT + (size_t)kBS * kH;        // 8 MB (total 32 MB)

  // bf16 stash in AW region: consumed by gemm_p before attn_fused writes AW
  unsigned short* stash = (unsigned short*)aw;
  unsigned short* QB  = stash;
  unsigned short* KB  = stash + (size_t)4194304;
  unsigned short* VB  = stash + (size_t)8388608;
  unsigned short* Wqb = stash + (size_t)12582912;
  unsigned short* Wkb = stash + (size_t)13631488;
  unsigned short* Wvb = stash + (size_t)14680064;

  cvt_all<<<dim3(2560, 3), 256, 0, stream>>>(q, k, v, Wq, Wk, Wv, stash);
  gemm_p<<<dim3(768), 256, 0, stream>>>(QB, KB, VB, Wqb, Wkb, Wvb, QP, KP, VPT);
  attn_fused<<<dim3(512), 256, 0, stream>>>(QP, KP, VPT, aw, XB);
  gemm_f<<<dim3(512), 256, 0, stream>>>(XB, Wo, out);
}